// Round 9
// baseline (223.478 us; speedup 1.0000x reference)
//
#include <hip/hip_runtime.h>

typedef unsigned short ushort_t;
typedef unsigned int uint_t;

#define NB 4
#define NC 128
#define NH 128
#define NW 128
#define NPIX 65536   // NB*NH*NW
#define NMID 32
#define NKK 49
#define NK 392
#define NKP 400      // NK padded to 25 n-tiles of 16
#define NO 256
#define LN_EPS 1e-6f

typedef __attribute__((ext_vector_type(8))) short short8;
typedef __attribute__((ext_vector_type(4))) float floatx4;

__device__ __forceinline__ float bf2f(ushort_t u) {
    union { uint_t i; float f; } v; v.i = ((uint_t)u) << 16; return v.f;
}
__device__ __forceinline__ float bf2f_lo(uint_t u) {
    union { uint_t i; float f; } v; v.i = u << 16; return v.f;
}
__device__ __forceinline__ float bf2f_hi(uint_t u) {
    union { uint_t i; float f; } v; v.i = u & 0xffff0000u; return v.f;
}
__device__ __forceinline__ ushort_t f2bf(float f) {
    union { float f; uint_t i; } v; v.f = f;
    uint_t x = v.i;
    uint_t r = (x + 0x7FFFu + ((x >> 16) & 1u)) >> 16;
    return (ushort_t)r;
}
__device__ __forceinline__ float gelu_f(float x) {
    return 0.5f * x * (1.0f + erff(x * 0.70710678118654752f));
}
__device__ __forceinline__ float ldin(const void* p, int i, int isf32) {
    return isf32 ? ((const float*)p)[i] : bf2f(((const ushort_t*)p)[i]);
}
// global -> LDS direct DMA, 16B per lane; LDS dest = uniform base + lane*16
__device__ __forceinline__ void gload_lds16(const void* g, void* l) {
    __builtin_amdgcn_global_load_lds(
        (const __attribute__((address_space(1))) void*)g,
        (__attribute__((address_space(3))) void*)l, 16, 0, 0);
}

// ---------------------------------------------------------------------------
// kdetect: runtime dtype sniff (exponent histogram). REQUIRED: the harness's
// in_sizes/out_size are ELEMENT COUNTS, not bytes (r8 post-mortem: host-side
// size-based detection read fp32 as bf16 -> NaN). Output dtype = input dtype,
// as validated in rounds 0-7.
// ---------------------------------------------------------------------------
__global__ void kdetect(const uint_t* __restrict__ xw, int* __restrict__ flag) {
    int lane = threadIdx.x;
    int cnt = 0;
    for (int j = 0; j < 8; j++) {
        uint_t w = xw[lane * 8 + j];
        uint_t e = (w >> 7) & 0xffu;
        if (e >= 110u && e <= 135u) cnt++;
    }
    for (int d = 1; d < 64; d <<= 1) cnt += __shfl_xor(cnt, d);
    if (lane == 0) flag[0] = (cnt < 256) ? 1 : 0;
}

__global__ void ksentinel(uint_t* __restrict__ out, int nwords) {
    int i = blockIdx.x * 256 + threadIdx.x;
    if (i < nwords) out[i] = 0x40004000u;
}

// ---------------------------------------------------------------------------
// K0a: transpose x (B,C,H,W) -> xT (B,H,W,C) canonical bf16.
// ---------------------------------------------------------------------------
__global__ __launch_bounds__(256) void ktrans(const void* __restrict__ x,
                                              ushort_t* __restrict__ xT,
                                              const int* __restrict__ flag) {
    int isf32 = flag[0];
    int b = blockIdx.z, h = blockIdx.y;
    int wchunk = blockIdx.x & 1, cchunk = blockIdx.x >> 1;
    int w0 = wchunk << 6, c0 = cchunk << 5;
    __shared__ ushort_t tile[32][66];
    int tx = threadIdx.x & 63, ty = threadIdx.x >> 6;
    for (int r = 0; r < 32; r += 4) {
        int idx = (((b * NC + c0 + r + ty) * NH) + h) * NW + w0 + tx;
        tile[r + ty][tx] = isf32 ? f2bf(((const float*)x)[idx])
                                 : ((const ushort_t*)x)[idx];
    }
    __syncthreads();
    int cc = threadIdx.x & 31, wq = threadIdx.x >> 5;
    for (int pp = 0; pp < 64; pp += 8) {
        int wx = pp + wq;
        xT[((size_t)((b * NH + h) * NW) + w0 + wx) * NC + c0 + cc] = tile[cc][wx];
    }
}

// ---------------------------------------------------------------------------
// KPREPFRAG: merged param-prep + conv/map fragment repack (was 2 dispatches).
// Blocks [0,128): kprep body. Blocks [128,160): kfrag body.
// kfrag chunk id cid = [kb:2][br:1][n4:4][lane:6], chunk = 8 bf16 = 16 B;
// each kb-tile (32 KB) contiguous -> linear global_load_lds target in k23.
// ---------------------------------------------------------------------------
__global__ __launch_bounds__(256) void kprepfrag(const void* w1, const void* w2,
                                                 const void* b1, const void* b2,
                                                 const void* ln1w, const void* ln1b,
                                                 const void* ln2w, const void* ln2b,
                                                 const void* map_b,
                                                 const void* ln3w, const void* ln3b,
                                                 const void* conv_w, const void* map_w,
                                                 const int* __restrict__ flag,
                                                 ushort_t* __restrict__ w1b,
                                                 ushort_t* __restrict__ w2b,
                                                 float* __restrict__ b1f,
                                                 float* __restrict__ b2f,
                                                 float* __restrict__ ln1wf,
                                                 float* __restrict__ ln1bf,
                                                 float* __restrict__ ln2wf,
                                                 float* __restrict__ ln2bf,
                                                 float* __restrict__ mbf,
                                                 float* __restrict__ ln3wf,
                                                 float* __restrict__ ln3bf,
                                                 ushort_t* __restrict__ wfrag) {
    int isf32 = flag[0];
    int bid = blockIdx.x;
    if (bid < 128) {
        int i = bid * 256 + threadIdx.x;
        if (i < NMID * NC) w1b[i] = f2bf(ldin(w1, i, isf32));
        if (i < NKP * NMID) w2b[i] = (i < NK * NMID) ? f2bf(ldin(w2, i, isf32))
                                                     : (ushort_t)0;
        if (i < NMID) b1f[i] = ldin(b1, i, isf32);
        if (i < NKP)  b2f[i] = (i < NK) ? ldin(b2, i, isf32) : 0.f;
        if (i < NC) { ln1wf[i] = ldin(ln1w, i, isf32); ln1bf[i] = ldin(ln1b, i, isf32); }
        if (i < NO) {
            ln2wf[i] = ldin(ln2w, i, isf32); ln2bf[i] = ldin(ln2b, i, isf32);
            mbf[i]   = ldin(map_b, i, isf32);
            ln3wf[i] = ldin(ln3w, i, isf32); ln3bf[i] = ldin(ln3b, i, isf32);
        }
    } else {
        int cid = (bid - 128) * 256 + threadIdx.x;   // [0, 8192)
        int lane = cid & 63, n4 = (cid >> 6) & 15, br = (cid >> 10) & 1, kb = cid >> 11;
        int o = n4 * 16 + (lane & 15);
        int ch0 = kb * 32 + (lane >> 4) * 8;
        const void* src = br ? map_w : conv_w;
        ushort_t* dst = wfrag + (size_t)cid * 8;
#pragma unroll
        for (int j = 0; j < 8; j++)
            dst[j] = f2bf(ldin(src, o * NC + ch0 + j, isf32));
    }
}

// ---------------------------------------------------------------------------
// K1F: fused wk-gen + involution + LN1 + GELU (replaces k1a + k1b + the 52MB
// wkT round-trip). Block 512 = 8 waves, tile 8x8 px, grid 1024.
// Phase A (wk-gen, same 132 MFMAs as k1a): waves 0-3 compute mid (1x1 conv ->
// ReLU) into midbuf; then all 8 waves compute wk = w2*mid+b2 into LDS
// wkstage[400][66] (wave w: px-block w&3, nt-range split 0..12 / 13..24).
// Phase B (involution): 8 lanes per px, 16 ch each; wk from LDS column,
// x from global uint4 pairs (8 g-lanes x 32B = 256B contiguous per px; the
// 14x14x256B halo is L1/L2-resident). LN via 3-step shfl tree over the 8
// g-lanes; gelu + pack + store y1. LDS 56.9 KB -> 2 blocks/CU, 16 waves/CU.
// ---------------------------------------------------------------------------
__global__ __launch_bounds__(512) void k1f(const ushort_t* __restrict__ xT,
                                           const ushort_t* __restrict__ w1b,
                                           const float* __restrict__ b1f,
                                           const ushort_t* __restrict__ w2b,
                                           const float* __restrict__ b2f,
                                           const float* __restrict__ ln1wf,
                                           const float* __restrict__ ln1bf,
                                           ushort_t* __restrict__ y1) {
    __shared__ ushort_t midbuf[64 * 32];
    __shared__ ushort_t wkstage[NKP * 66];

    int t = threadIdx.x;
    int lane = t & 63;
    int w = __builtin_amdgcn_readfirstlane(t >> 6);   // 0..7
    int l16 = lane & 15, quad = lane >> 4;
    int tileid = blockIdx.x;
    int tilex = tileid & 15, tiley = (tileid >> 4) & 15, b = tileid >> 8;
    int h0 = tiley * 8, w0 = tilex * 8;
    int w4 = w & 3;

    // ---- Phase A1: mid = relu(w1 @ x + b1), waves 0..3 (16 px each) ----
    if (w < 4) {
        int lpx = 16 * w + l16;
        int py = lpx >> 3, pxx = lpx & 7;
        const ushort_t* abase = xT + (size_t)((b * NH + h0 + py) * NW + w0 + pxx) * NC + quad * 8;
        floatx4 am0 = (floatx4)0.f, am1 = (floatx4)0.f;
#pragma unroll
        for (int kb = 0; kb < 4; kb++) {
            short8 a   = *(const short8*)(abase + kb * 32);
            short8 b0  = *(const short8*)(w1b + (l16) * NC + kb * 32 + quad * 8);
            short8 b1v = *(const short8*)(w1b + (16 + l16) * NC + kb * 32 + quad * 8);
            am0 = __builtin_amdgcn_mfma_f32_16x16x32_bf16(a, b0, am0, 0, 0, 0);
            am1 = __builtin_amdgcn_mfma_f32_16x16x32_bf16(a, b1v, am1, 0, 0, 0);
        }
        float bia0 = b1f[l16], bia1 = b1f[16 + l16];
#pragma unroll
        for (int r = 0; r < 4; r++) {
            int m = 16 * w + quad * 4 + r;
            midbuf[m * 32 + l16]      = f2bf(fmaxf(am0[r] + bia0, 0.f));
            midbuf[m * 32 + 16 + l16] = f2bf(fmaxf(am1[r] + bia1, 0.f));
        }
    }
    __syncthreads();

    // ---- Phase A2: wk = w2 @ mid + b2 -> wkstage[n][px] (8 waves) ----
    {
        short8 aM = *(const short8*)(midbuf + (16 * w4 + l16) * 32 + quad * 8);
        int nt0 = (w < 4) ? 0 : 13;
        int nt1 = (w < 4) ? 13 : 25;
        for (int nt = nt0; nt < nt1; nt++) {
            int n = nt * 16 + l16;
            short8 bw = *(const short8*)(w2b + n * 32 + quad * 8);
            floatx4 c = __builtin_amdgcn_mfma_f32_16x16x32_bf16(aM, bw, (floatx4)0.f, 0, 0, 0);
            float bias = b2f[n];
#pragma unroll
            for (int r = 0; r < 4; r++)
                wkstage[n * 66 + 16 * w4 + quad * 4 + r] = f2bf(c[r] + bias);
        }
    }
    __syncthreads();

    // ---- Phase B: involution + LN1 + GELU. 8 lanes per px, 16 ch each ----
    int px = t >> 3, g = t & 7;
    int hy = px >> 3, hx = px & 7;
    int hh0 = h0 + hy, ww0 = w0 + hx;
    int p = (b * NH + hh0) * NW + ww0;
    const ushort_t* wkcol = wkstage + px;

    float a[16];
#pragma unroll
    for (int j = 0; j < 16; j++) a[j] = 0.f;

#pragma unroll
    for (int dy = -3; dy <= 3; dy++) {
        int hh = hh0 + dy;
        if ((unsigned)hh >= (unsigned)NH) continue;
#pragma unroll
        for (int dx = -3; dx <= 3; dx++) {
            int ww = ww0 + dx;
            if ((unsigned)ww >= (unsigned)NW) continue;
            int tap = (dy + 3) * 7 + (dx + 3);
            float wkv = bf2f(wkcol[(g * NKK + tap) * 66]);
            const uint4* xq = (const uint4*)(xT + (size_t)(p + dy * NW + dx) * NC + g * 16);
            uint4 u0 = xq[0], u1 = xq[1];
            a[0]  = fmaf(wkv, bf2f_lo(u0.x), a[0]);
            a[1]  = fmaf(wkv, bf2f_hi(u0.x), a[1]);
            a[2]  = fmaf(wkv, bf2f_lo(u0.y), a[2]);
            a[3]  = fmaf(wkv, bf2f_hi(u0.y), a[3]);
            a[4]  = fmaf(wkv, bf2f_lo(u0.z), a[4]);
            a[5]  = fmaf(wkv, bf2f_hi(u0.z), a[5]);
            a[6]  = fmaf(wkv, bf2f_lo(u0.w), a[6]);
            a[7]  = fmaf(wkv, bf2f_hi(u0.w), a[7]);
            a[8]  = fmaf(wkv, bf2f_lo(u1.x), a[8]);
            a[9]  = fmaf(wkv, bf2f_hi(u1.x), a[9]);
            a[10] = fmaf(wkv, bf2f_lo(u1.y), a[10]);
            a[11] = fmaf(wkv, bf2f_hi(u1.y), a[11]);
            a[12] = fmaf(wkv, bf2f_lo(u1.z), a[12]);
            a[13] = fmaf(wkv, bf2f_hi(u1.z), a[13]);
            a[14] = fmaf(wkv, bf2f_lo(u1.w), a[14]);
            a[15] = fmaf(wkv, bf2f_hi(u1.w), a[15]);
        }
    }

    // LN over 128 ch: partial (16 ch) -> shfl tree over the 8 g-lanes
    float s = 0.f, sq = 0.f;
#pragma unroll
    for (int j = 0; j < 16; j++) { s += a[j]; sq += a[j] * a[j]; }
#pragma unroll
    for (int d = 1; d < 8; d <<= 1) {
        s  += __shfl_xor(s, d);
        sq += __shfl_xor(sq, d);
    }
    float mean = s * (1.0f / NC);
    float var = sq * (1.0f / NC) - mean * mean;
    float rstd = rsqrtf(var + LN_EPS);

    uint_t pk[8];
#pragma unroll
    for (int j = 0; j < 8; j++) {
        int c0 = g * 16 + 2 * j;
        float g0 = gelu_f((a[2 * j] - mean) * rstd * ln1wf[c0] + ln1bf[c0]);
        float g1 = gelu_f((a[2 * j + 1] - mean) * rstd * ln1wf[c0 + 1] + ln1bf[c0 + 1]);
        pk[j] = (uint_t)f2bf(g0) | ((uint_t)f2bf(g1) << 16);
    }
    uint4* dst = (uint4*)(y1 + (size_t)p * NC + g * 16);
    dst[0] = make_uint4(pk[0], pk[1], pk[2], pk[3]);
    dst[1] = make_uint4(pk[4], pk[5], pk[6], pk[7]);
}

// ---------------------------------------------------------------------------
// K23 v10 (structure unchanged from round 7; flag-based isf32 restored).
// o-half split wave pairs; LDS-staged B via global_load_lds; streaming
// epilogue; 64 VGPR + 64 AGPR, no spill. grid 2048, block 256.
// ---------------------------------------------------------------------------
__global__ __launch_bounds__(256, 4) void k23(const ushort_t* __restrict__ y1,
                                              const ushort_t* __restrict__ xT,
                                              const ushort_t* __restrict__ wfrag,
                                              const float* __restrict__ mbf,
                                              const float* __restrict__ ln2wf,
                                              const float* __restrict__ ln2bf,
                                              const float* __restrict__ ln3wf,
                                              const float* __restrict__ ln3bf,
                                              void* __restrict__ out,
                                              const int* __restrict__ flag) {
    __shared__ __align__(16) char sbuf[32768];   // B stage, reused for stats

    int isf32 = flag[0];
    int t = threadIdx.x;
    int lane = t & 63;
    int w = __builtin_amdgcn_readfirstlane(t >> 6);   // 0..3
    int quad = lane >> 4, l16 = lane & 15;
    int pair = w >> 1;                                // 0..1 -> px group
    int oh   = w & 1;                                 // 0..1 -> o-half (128 o's)

    int P0 = blockIdx.x * 32;
    int pw = P0 + pair * 16;                          // this wave's first pixel
    const ushort_t* aYp = y1 + (size_t)(pw + l16) * NC + quad * 8;
    const ushort_t* aXp = xT + (size_t)(pw + l16) * NC + quad * 8;

    // stage kb=0 B-tile (32KB): wave w covers chunks [w*512, w*512+512)
    {
        const ushort_t* gsrc = wfrag + (size_t)(w * 512 + lane) * 8;
        char* ldst = sbuf + (size_t)(w * 512) * 16;
#pragma unroll
        for (int i = 0; i < 8; i++)
            gload_lds16(gsrc + i * 64 * 8, ldst + i * 64 * 16);
    }
    // A operands (both branches) for all 4 k-blocks, hoisted to registers
    short8 Ay[4], Ax[4];
#pragma unroll
    for (int kb = 0; kb < 4; kb++) {
        Ay[kb] = *(const short8*)(aYp + kb * 32);
        Ax[kb] = *(const short8*)(aXp + kb * 32);
    }
    __syncthreads();

    floatx4 accC[8], accM[8];
#pragma unroll
    for (int j = 0; j < 8; j++) { accC[j] = (floatx4)0.f; accM[j] = (floatx4)0.f; }

#pragma unroll
    for (int kb = 0; kb < 4; kb++) {
        short8 ay = Ay[kb], ax = Ax[kb];
#pragma unroll
        for (int j = 0; j < 8; j++) {
            int n4 = oh * 8 + j;
            // tile layout: [br:1][n4:4][lane:6] chunks of 16 B
            short8 bc = *(const short8*)(sbuf + (size_t)(n4 * 64 + lane) * 16);
            short8 bm = *(const short8*)(sbuf + 16384 + (size_t)(n4 * 64 + lane) * 16);
            accC[j] = __builtin_amdgcn_mfma_f32_16x16x32_bf16(ay, bc, accC[j], 0, 0, 0);
            accM[j] = __builtin_amdgcn_mfma_f32_16x16x32_bf16(ax, bm, accM[j], 0, 0, 0);
        }
        __syncthreads();                              // all B reads done
        if (kb < 3) {
            const ushort_t* gsrc = wfrag + ((size_t)(kb + 1) * 2048 + w * 512 + lane) * 8;
            char* ldst = sbuf + (size_t)(w * 512) * 16;
#pragma unroll
            for (int i = 0; i < 8; i++)
                gload_lds16(gsrc + i * 64 * 8, ldst + i * 64 * 16);
            __syncthreads();                          // staging visible (vmcnt drained)
        }
    }

    // map-branch bias (before LN3 stats)
#pragma unroll
    for (int j = 0; j < 8; j++) {
        float mb = mbf[(oh * 8 + j) * 16 + l16];
#pragma unroll
        for (int r = 0; r < 4; r++) accM[j][r] += mb;
    }

    // LN partial stats per px (px = quad*4 + r) over this wave's 128 o's
    floatx4 s1 = (floatx4)0.f, q1 = (floatx4)0.f, s2 = (floatx4)0.f, q2 = (floatx4)0.f;
#pragma unroll
    for (int j = 0; j < 8; j++)
#pragma unroll
        for (int r = 0; r < 4; r++) {
            float a = accC[j][r], m = accM[j][r];
            s1[r] += a; q1[r] += a * a;
            s2[r] += m; q2[r] += m * m;
        }
#pragma unroll
    for (int d = 1; d < 16; d <<= 1) {
#pragma unroll
        for (int r = 0; r < 4; r++) {
            s1[r] += __shfl_xor(s1[r], d);
            q1[r] += __shfl_xor(q1[r], d);
            s2[r] += __shfl_xor(s2[r], d);
            q2[r] += __shfl_xor(q2[r], d);
        }
    }

    // exchange partial stats with the pair's other o-half through sbuf (dead)
    float* sstat = (float*)sbuf;
    if (l16 == 0) {
#pragma unroll
        for (int r = 0; r < 4; r++) {
            float* sp = sstat + (((pair * 2 + oh) * 16) + quad * 4 + r) * 4;
            sp[0] = s1[r]; sp[1] = q1[r]; sp[2] = s2[r]; sp[3] = q2[r];
        }
    }
    __syncthreads();

    floatx4 mn1, rs1, mn2, rs2;
#pragma unroll
    for (int r = 0; r < 4; r++) {
        const float* op = sstat + (((pair * 2 + (oh ^ 1)) * 16) + quad * 4 + r) * 4;
        float S1 = s1[r] + op[0], Q1 = q1[r] + op[1];
        float S2 = s2[r] + op[2], Q2 = q2[r] + op[3];
        mn1[r] = S1 * (1.0f / NO);
        rs1[r] = rsqrtf(Q1 * (1.0f / NO) - mn1[r] * mn1[r] + LN_EPS);
        mn2[r] = S2 * (1.0f / NO);
        rs2[r] = rsqrtf(Q2 * (1.0f / NO) - mn2[r] * mn2[r] + LN_EPS);
    }

    // streaming epilogue: per n4, normalize both branches, gelu, direct store
    int batch = pw >> 14;
    int plocal = (pw & 16383) + quad * 4;
#pragma unroll
    for (int j = 0; j < 8; j++) {
        int o = (oh * 8 + j) * 16 + l16;
        float l2w = ln2wf[o], l2b = ln2bf[o];
        float l3w = ln3wf[o], l3b = ln3bf[o];
        float4 gv;
        {
            float v1, v2;
            v1 = (accC[j][0] - mn1[0]) * rs1[0] * l2w + l2b;
            v2 = (accM[j][0] - mn2[0]) * rs2[0] * l3w + l3b;
            gv.x = gelu_f(v1 + v2);
            v1 = (accC[j][1] - mn1[1]) * rs1[1] * l2w + l2b;
            v2 = (accM[j][1] - mn2[1]) * rs2[1] * l3w + l3b;
            gv.y = gelu_f(v1 + v2);
            v1 = (accC[j][2] - mn1[2]) * rs1[2] * l2w + l2b;
            v2 = (accM[j][2] - mn2[2]) * rs2[2] * l3w + l3b;
            gv.z = gelu_f(v1 + v2);
            v1 = (accC[j][3] - mn1[3]) * rs1[3] * l2w + l2b;
            v2 = (accM[j][3] - mn2[3]) * rs2[3] * l3w + l3b;
            gv.w = gelu_f(v1 + v2);
        }
        size_t oi = ((size_t)(batch * NO + o) << 14) + plocal;
        if (isf32) {
            *(float4*)((float*)out + oi) = gv;
        } else {
            uint_t p0 = (uint_t)f2bf(gv.x) | ((uint_t)f2bf(gv.y) << 16);
            uint_t p1 = (uint_t)f2bf(gv.z) | ((uint_t)f2bf(gv.w) << 16);
            *(uint2*)((ushort_t*)out + oi) = make_uint2(p0, p1);
        }
    }
}

// ---------------------------------------------------------------------------
extern "C" void kernel_launch(void* const* d_in, const int* in_sizes, int n_in,
                              void* d_out, int out_size, void* d_ws, size_t ws_size,
                              hipStream_t stream) {
    const void* x      = d_in[0];
    const void* w1     = d_in[1];
    const void* b1     = d_in[2];
    const void* w2     = d_in[3];
    const void* b2     = d_in[4];
    const void* ln1w   = d_in[5];
    const void* ln1b   = d_in[6];
    const void* conv_w = d_in[7];
    const void* ln2w   = d_in[8];
    const void* ln2b   = d_in[9];
    const void* map_w  = d_in[10];
    const void* map_b  = d_in[11];
    const void* ln3w   = d_in[12];
    const void* ln3b   = d_in[13];

    char* ws = (char*)d_ws;
    ushort_t* xT    = (ushort_t*)(ws);                  // 16,777,216 B
    ushort_t* y1    = (ushort_t*)(ws + 16777216);       // 16,777,216 B
    ushort_t* wfrag = (ushort_t*)(ws + 33554432);       // 131,072 B
    ushort_t* w1b   = (ushort_t*)(ws + 33685504);       //   8,192 B
    ushort_t* w2b   = (ushort_t*)(ws + 33693696);       //  25,600 B
    float*    b1f   = (float*)(ws + 33719296);
    float*    b2f   = (float*)(ws + 33719424);
    float*    ln1wf = (float*)(ws + 33721024);
    float*    ln1bf = (float*)(ws + 33721536);
    float*    mbf   = (float*)(ws + 33722048);
    float*    ln2wf = (float*)(ws + 33723072);
    float*    ln2bf = (float*)(ws + 33724096);
    float*    ln3wf = (float*)(ws + 33725120);
    float*    ln3bf = (float*)(ws + 33726144);
    int*      flag  = (int*)(ws + 33727168);
    const size_t NEED_SMALL = 33727184;

    if (ws_size < NEED_SMALL) {
        int nwords = out_size / 2;
        ksentinel<<<(nwords + 255) / 256, 256, 0, stream>>>((uint_t*)d_out, nwords);
        return;
    }

    kdetect<<<1, 64, 0, stream>>>((const uint_t*)x, flag);
    kprepfrag<<<160, 256, 0, stream>>>(w1, w2, b1, b2, ln1w, ln1b,
                                       ln2w, ln2b, map_b, ln3w, ln3b,
                                       conv_w, map_w, flag,
                                       w1b, w2b, b1f, b2f, ln1wf, ln1bf,
                                       ln2wf, ln2bf, mbf, ln3wf, ln3bf, wfrag);
    ktrans<<<dim3(8, 128, 4), 256, 0, stream>>>(x, xT, flag);
    k1f<<<1024, 512, 0, stream>>>(xT, w1b, b1f, w2b, b2f, ln1wf, ln1bf, y1);
    k23<<<NPIX / 32, 256, 0, stream>>>(y1, xT, wfrag, mbf,
                                       ln2wf, ln2bf, ln3wf, ln3bf, d_out, flag);
}

// Round 10
// 206.338 us; speedup vs baseline: 1.0831x; 1.0831x over previous
//
#include <hip/hip_runtime.h>

typedef unsigned short ushort_t;
typedef unsigned int uint_t;

#define NB 4
#define NC 128
#define NH 128
#define NW 128
#define NPIX 65536   // NB*NH*NW
#define NMID 32
#define NKK 49
#define NK 392
#define NKP 400      // NK padded to 25 n-tiles of 16
#define NO 256
#define LN_EPS 1e-6f

typedef __attribute__((ext_vector_type(8))) short short8;
typedef __attribute__((ext_vector_type(4))) float floatx4;

__device__ __forceinline__ float bf2f(ushort_t u) {
    union { uint_t i; float f; } v; v.i = ((uint_t)u) << 16; return v.f;
}
__device__ __forceinline__ float bf2f_lo(uint_t u) {
    union { uint_t i; float f; } v; v.i = u << 16; return v.f;
}
__device__ __forceinline__ float bf2f_hi(uint_t u) {
    union { uint_t i; float f; } v; v.i = u & 0xffff0000u; return v.f;
}
__device__ __forceinline__ ushort_t f2bf(float f) {
    union { float f; uint_t i; } v; v.f = f;
    uint_t x = v.i;
    uint_t r = (x + 0x7FFFu + ((x >> 16) & 1u)) >> 16;
    return (ushort_t)r;
}
__device__ __forceinline__ float gelu_f(float x) {
    return 0.5f * x * (1.0f + erff(x * 0.70710678118654752f));
}
__device__ __forceinline__ float ldin(const void* p, int i, int isf32) {
    return isf32 ? ((const float*)p)[i] : bf2f(((const ushort_t*)p)[i]);
}
// global -> LDS direct DMA, 16B per lane; LDS dest = uniform base + lane*16
__device__ __forceinline__ void gload_lds16(const void* g, void* l) {
    __builtin_amdgcn_global_load_lds(
        (const __attribute__((address_space(1))) void*)g,
        (__attribute__((address_space(3))) void*)l, 16, 0, 0);
}

// ---------------------------------------------------------------------------
// Per-block dtype sniff (replaces the kdetect dispatch). Exponent histogram
// over x's first 512 words; deterministic across blocks (same bytes). One
// wave computes, result broadcast via LDS. in_sizes are ELEMENT counts (r8
// post-mortem), so runtime sniffing is required.
// ---------------------------------------------------------------------------
__device__ __forceinline__ int sniff_isf32(const void* x, int* lf) {
    int t = threadIdx.x;
    if (t < 64) {
        const uint_t* xw = (const uint_t*)x;
        int cnt = 0;
#pragma unroll
        for (int j = 0; j < 8; j++) {
            uint_t wv = xw[t * 8 + j];
            uint_t e = (wv >> 7) & 0xffu;
            if (e >= 110u && e <= 135u) cnt++;
        }
#pragma unroll
        for (int d = 1; d < 64; d <<= 1) cnt += __shfl_xor(cnt, d);
        if (t == 0) *lf = (cnt < 256) ? 1 : 0;
    }
    __syncthreads();
    return *lf;
}

__global__ void ksentinel(uint_t* __restrict__ out, int nwords) {
    int i = blockIdx.x * 256 + threadIdx.x;
    if (i < nwords) out[i] = 0x40004000u;
}

// ---------------------------------------------------------------------------
// K0a: transpose x (B,C,H,W) -> xT (B,H,W,C) canonical bf16. Local sniff.
// ---------------------------------------------------------------------------
__global__ __launch_bounds__(256) void ktrans(const void* __restrict__ x,
                                              ushort_t* __restrict__ xT) {
    __shared__ ushort_t tile[32][66];
    __shared__ int lf;
    int isf32 = sniff_isf32(x, &lf);
    int b = blockIdx.z, h = blockIdx.y;
    int wchunk = blockIdx.x & 1, cchunk = blockIdx.x >> 1;
    int w0 = wchunk << 6, c0 = cchunk << 5;
    int tx = threadIdx.x & 63, ty = threadIdx.x >> 6;
    for (int r = 0; r < 32; r += 4) {
        int idx = (((b * NC + c0 + r + ty) * NH) + h) * NW + w0 + tx;
        tile[r + ty][tx] = isf32 ? f2bf(((const float*)x)[idx])
                                 : ((const ushort_t*)x)[idx];
    }
    __syncthreads();
    int cc = threadIdx.x & 31, wq = threadIdx.x >> 5;
    for (int pp = 0; pp < 64; pp += 8) {
        int wx = pp + wq;
        xT[((size_t)((b * NH + h) * NW) + w0 + wx) * NC + c0 + cc] = tile[cc][wx];
    }
}

// ---------------------------------------------------------------------------
// KPREPFRAG: merged param-prep + conv/map fragment repack. Local sniff.
// Blocks [0,128): kprep body. Blocks [128,160): kfrag body.
// kfrag chunk id cid = [kb:2][br:1][n4:4][lane:6], chunk = 8 bf16 = 16 B;
// each kb-tile (32 KB) contiguous -> linear global_load_lds target in k23.
// ---------------------------------------------------------------------------
__global__ __launch_bounds__(256) void kprepfrag(const void* x,
                                                 const void* w1, const void* w2,
                                                 const void* b1, const void* b2,
                                                 const void* ln1w, const void* ln1b,
                                                 const void* ln2w, const void* ln2b,
                                                 const void* map_b,
                                                 const void* ln3w, const void* ln3b,
                                                 const void* conv_w, const void* map_w,
                                                 ushort_t* __restrict__ w1b,
                                                 ushort_t* __restrict__ w2b,
                                                 float* __restrict__ b1f,
                                                 float* __restrict__ b2f,
                                                 float* __restrict__ ln1wf,
                                                 float* __restrict__ ln1bf,
                                                 float* __restrict__ ln2wf,
                                                 float* __restrict__ ln2bf,
                                                 float* __restrict__ mbf,
                                                 float* __restrict__ ln3wf,
                                                 float* __restrict__ ln3bf,
                                                 ushort_t* __restrict__ wfrag) {
    __shared__ int lf;
    int isf32 = sniff_isf32(x, &lf);
    int bid = blockIdx.x;
    if (bid < 128) {
        int i = bid * 256 + threadIdx.x;
        if (i < NMID * NC) w1b[i] = f2bf(ldin(w1, i, isf32));
        if (i < NKP * NMID) w2b[i] = (i < NK * NMID) ? f2bf(ldin(w2, i, isf32))
                                                     : (ushort_t)0;
        if (i < NMID) b1f[i] = ldin(b1, i, isf32);
        if (i < NKP)  b2f[i] = (i < NK) ? ldin(b2, i, isf32) : 0.f;
        if (i < NC) { ln1wf[i] = ldin(ln1w, i, isf32); ln1bf[i] = ldin(ln1b, i, isf32); }
        if (i < NO) {
            ln2wf[i] = ldin(ln2w, i, isf32); ln2bf[i] = ldin(ln2b, i, isf32);
            mbf[i]   = ldin(map_b, i, isf32);
            ln3wf[i] = ldin(ln3w, i, isf32); ln3bf[i] = ldin(ln3b, i, isf32);
        }
    } else {
        int cid = (bid - 128) * 256 + threadIdx.x;   // [0, 8192)
        int lane = cid & 63, n4 = (cid >> 6) & 15, br = (cid >> 10) & 1, kb = cid >> 11;
        int o = n4 * 16 + (lane & 15);
        int ch0 = kb * 32 + (lane >> 4) * 8;
        const void* src = br ? map_w : conv_w;
        ushort_t* dst = wfrag + (size_t)cid * 8;
#pragma unroll
        for (int j = 0; j < 8; j++)
            dst[j] = f2bf(ldin(src, o * NC + ch0 + j, isf32));
    }
}

// ---------------------------------------------------------------------------
// K1F v2: fused wk-gen + involution + LN1 + GELU, with LDS TIME-MULTIPLEXED:
// phase A writes wk into wkstage (52.8 KB); each lane then PRELOADS its wk
// column into 25 packed regs (k1b's wkp; conflict-free 64-consecutive-ushort
// row reads); barrier; the SAME LDS is overwritten with k1b's x8 halo buffer
// (50.4 KB, read ONCE from L2 instead of 49x per px via L1/L2/L3 = 822 MB ->
// 51 MB, r9's diagnosed stall source); phase B is k1b's proven tap loop /
// LN / store verbatim. LDS 56.9 KB -> 2 blocks/CU. Block 512, grid 1024.
// ---------------------------------------------------------------------------
__global__ __launch_bounds__(512) void k1f(const ushort_t* __restrict__ xT,
                                           const ushort_t* __restrict__ w1b,
                                           const float* __restrict__ b1f,
                                           const ushort_t* __restrict__ w2b,
                                           const float* __restrict__ b2f,
                                           const float* __restrict__ ln1wf,
                                           const float* __restrict__ ln1bf,
                                           ushort_t* __restrict__ y1) {
    __shared__ __align__(16) char smem[52800];   // wkstage, then x8/sred
    __shared__ ushort_t midbuf[64 * 32];
    ushort_t* wkstage = (ushort_t*)smem;
    uint4*    x8      = (uint4*)smem;
    float*    sred    = (float*)smem;

    int t = threadIdx.x;
    int lane = t & 63;
    int w = __builtin_amdgcn_readfirstlane(t >> 6);   // 0..7
    int l16 = lane & 15, quad = lane >> 4;
    int tileid = blockIdx.x;
    int tilex = tileid & 15, tiley = (tileid >> 4) & 15, b = tileid >> 8;
    int h0 = tiley * 8, w0 = tilex * 8;
    int w4 = w & 3;

    // ---- Phase A1: mid = relu(w1 @ x + b1), waves 0..3 (16 px each) ----
    if (w < 4) {
        int lpx = 16 * w + l16;
        int py = lpx >> 3, pxx = lpx & 7;
        const ushort_t* abase = xT + (size_t)((b * NH + h0 + py) * NW + w0 + pxx) * NC + quad * 8;
        floatx4 am0 = (floatx4)0.f, am1 = (floatx4)0.f;
#pragma unroll
        for (int kb = 0; kb < 4; kb++) {
            short8 a   = *(const short8*)(abase + kb * 32);
            short8 b0  = *(const short8*)(w1b + (l16) * NC + kb * 32 + quad * 8);
            short8 b1v = *(const short8*)(w1b + (16 + l16) * NC + kb * 32 + quad * 8);
            am0 = __builtin_amdgcn_mfma_f32_16x16x32_bf16(a, b0, am0, 0, 0, 0);
            am1 = __builtin_amdgcn_mfma_f32_16x16x32_bf16(a, b1v, am1, 0, 0, 0);
        }
        float bia0 = b1f[l16], bia1 = b1f[16 + l16];
#pragma unroll
        for (int r = 0; r < 4; r++) {
            int m = 16 * w + quad * 4 + r;
            midbuf[m * 32 + l16]      = f2bf(fmaxf(am0[r] + bia0, 0.f));
            midbuf[m * 32 + 16 + l16] = f2bf(fmaxf(am1[r] + bia1, 0.f));
        }
    }
    __syncthreads();

    // ---- Phase A2: wk = w2 @ mid + b2 -> wkstage[n][px] (8 waves) ----
    {
        short8 aM = *(const short8*)(midbuf + (16 * w4 + l16) * 32 + quad * 8);
        int nt0 = (w < 4) ? 0 : 13;
        int nt1 = (w < 4) ? 13 : 25;
        for (int nt = nt0; nt < nt1; nt++) {
            int n = nt * 16 + l16;
            short8 bw = *(const short8*)(w2b + n * 32 + quad * 8);
            floatx4 c = __builtin_amdgcn_mfma_f32_16x16x32_bf16(aM, bw, (floatx4)0.f, 0, 0, 0);
            float bias = b2f[n];
#pragma unroll
            for (int r = 0; r < 4; r++)
                wkstage[n * 66 + 16 * w4 + quad * 4 + r] = f2bf(c[r] + bias);
        }
    }
    __syncthreads();

    // ---- wkp preload: lane = px, wave w = group w. Rows are 64 consecutive
    // ushorts -> conflict-free. 25 packed regs per lane (k1b's layout). ----
    uint_t wkp[25];
#pragma unroll
    for (int j = 0; j < 24; j++) {
        uint_t lo = wkstage[(w * NKK + 2 * j) * 66 + lane];
        uint_t hi = wkstage[(w * NKK + 2 * j + 1) * 66 + lane];
        wkp[j] = lo | (hi << 16);
    }
    wkp[24] = wkstage[(w * NKK + 48) * 66 + lane];
    __syncthreads();        // all wk reads complete before LDS reuse

    // ---- Halo staging into x8 (overwrites wkstage area; k1b verbatim) ----
    for (int it = 0; it < 7; it++) {
        int idx = it * 512 + t;
        if (idx < 3136) {
            int oct = idx & 15, hp = idx >> 4;
            int hy = hp / 14, hx = hp - hy * 14;
            int gh = h0 + hy - 3, gw = w0 + hx - 3;
            uint4 v = make_uint4(0u, 0u, 0u, 0u);
            if ((unsigned)gh < (unsigned)NH && (unsigned)gw < (unsigned)NW) {
                v = *(const uint4*)&xT[(size_t)((b * NH + gh) * NW + gw) * NC + 8 * oct];
            }
            x8[oct * 197 + hp] = v;
        }
    }
    __syncthreads();

    // ---- Phase B: involution from LDS (k1b verbatim) ----
    int py = lane >> 3, pxx = lane & 7;
    int base0 = py * 14 + pxx;
    float a[16];
#pragma unroll
    for (int j = 0; j < 16; j++) a[j] = 0.f;

#pragma unroll
    for (int tap = 0; tap < NKK; tap++) {
        float wkf = (tap & 1) ? bf2f((ushort_t)(wkp[tap >> 1] >> 16))
                              : bf2f((ushort_t)(wkp[tap >> 1] & 0xffffu));
        int xa = base0 + (tap / 7) * 14 + (tap % 7);
        uint4 u0 = x8[(2 * w) * 197 + xa];
        uint4 u1 = x8[(2 * w + 1) * 197 + xa];
        a[0]  = fmaf(wkf, bf2f_lo(u0.x), a[0]);
        a[1]  = fmaf(wkf, bf2f_hi(u0.x), a[1]);
        a[2]  = fmaf(wkf, bf2f_lo(u0.y), a[2]);
        a[3]  = fmaf(wkf, bf2f_hi(u0.y), a[3]);
        a[4]  = fmaf(wkf, bf2f_lo(u0.z), a[4]);
        a[5]  = fmaf(wkf, bf2f_hi(u0.z), a[5]);
        a[6]  = fmaf(wkf, bf2f_lo(u0.w), a[6]);
        a[7]  = fmaf(wkf, bf2f_hi(u0.w), a[7]);
        a[8]  = fmaf(wkf, bf2f_lo(u1.x), a[8]);
        a[9]  = fmaf(wkf, bf2f_hi(u1.x), a[9]);
        a[10] = fmaf(wkf, bf2f_lo(u1.y), a[10]);
        a[11] = fmaf(wkf, bf2f_hi(u1.y), a[11]);
        a[12] = fmaf(wkf, bf2f_lo(u1.z), a[12]);
        a[13] = fmaf(wkf, bf2f_hi(u1.z), a[13]);
        a[14] = fmaf(wkf, bf2f_lo(u1.w), a[14]);
        a[15] = fmaf(wkf, bf2f_hi(u1.w), a[15]);
    }
    __syncthreads();

    // ---- LN1 over 128 ch (k1b verbatim: block-wide sred reduction) ----
    float s = 0.f, sq = 0.f;
#pragma unroll
    for (int j = 0; j < 16; j++) { s += a[j]; sq += a[j] * a[j]; }
    sred[(w * 64 + lane) * 2]     = s;
    sred[(w * 64 + lane) * 2 + 1] = sq;
    __syncthreads();
    float ts = 0.f, tq = 0.f;
#pragma unroll
    for (int r = 0; r < 8; r++) {
        ts += sred[(r * 64 + lane) * 2];
        tq += sred[(r * 64 + lane) * 2 + 1];
    }
    float mean = ts * (1.0f / NC);
    float var = tq * (1.0f / NC) - mean * mean;
    float rstd = rsqrtf(var + LN_EPS);

    int p = (b * NH + h0 + py) * NW + w0 + pxx;
    uint_t pk[8];
#pragma unroll
    for (int j = 0; j < 8; j++) {
        int c0 = 16 * w + 2 * j;
        float g0 = gelu_f((a[2 * j] - mean) * rstd * ln1wf[c0] + ln1bf[c0]);
        float g1 = gelu_f((a[2 * j + 1] - mean) * rstd * ln1wf[c0 + 1] + ln1bf[c0 + 1]);
        pk[j] = (uint_t)f2bf(g0) | ((uint_t)f2bf(g1) << 16);
    }
    uint4* dst = (uint4*)(y1 + (size_t)p * NC + 16 * w);
    dst[0] = make_uint4(pk[0], pk[1], pk[2], pk[3]);
    dst[1] = make_uint4(pk[4], pk[5], pk[6], pk[7]);
}

// ---------------------------------------------------------------------------
// K23 v10 (structure unchanged; local sniff replaces flag). o-half split wave
// pairs; LDS-staged B via global_load_lds; streaming epilogue; 64 VGPR +
// 64 AGPR, no spill. grid 2048, block 256.
// ---------------------------------------------------------------------------
__global__ __launch_bounds__(256, 4) void k23(const void* __restrict__ x,
                                              const ushort_t* __restrict__ y1,
                                              const ushort_t* __restrict__ xT,
                                              const ushort_t* __restrict__ wfrag,
                                              const float* __restrict__ mbf,
                                              const float* __restrict__ ln2wf,
                                              const float* __restrict__ ln2bf,
                                              const float* __restrict__ ln3wf,
                                              const float* __restrict__ ln3bf,
                                              void* __restrict__ out) {
    __shared__ __align__(16) char sbuf[32768];   // B stage, reused for stats
    __shared__ int lf;
    int isf32 = sniff_isf32(x, &lf);

    int t = threadIdx.x;
    int lane = t & 63;
    int w = __builtin_amdgcn_readfirstlane(t >> 6);   // 0..3
    int quad = lane >> 4, l16 = lane & 15;
    int pair = w >> 1;                                // 0..1 -> px group
    int oh   = w & 1;                                 // 0..1 -> o-half (128 o's)

    int P0 = blockIdx.x * 32;
    int pw = P0 + pair * 16;                          // this wave's first pixel
    const ushort_t* aYp = y1 + (size_t)(pw + l16) * NC + quad * 8;
    const ushort_t* aXp = xT + (size_t)(pw + l16) * NC + quad * 8;

    // stage kb=0 B-tile (32KB): wave w covers chunks [w*512, w*512+512)
    {
        const ushort_t* gsrc = wfrag + (size_t)(w * 512 + lane) * 8;
        char* ldst = sbuf + (size_t)(w * 512) * 16;
#pragma unroll
        for (int i = 0; i < 8; i++)
            gload_lds16(gsrc + i * 64 * 8, ldst + i * 64 * 16);
    }
    // A operands (both branches) for all 4 k-blocks, hoisted to registers
    short8 Ay[4], Ax[4];
#pragma unroll
    for (int kb = 0; kb < 4; kb++) {
        Ay[kb] = *(const short8*)(aYp + kb * 32);
        Ax[kb] = *(const short8*)(aXp + kb * 32);
    }
    __syncthreads();

    floatx4 accC[8], accM[8];
#pragma unroll
    for (int j = 0; j < 8; j++) { accC[j] = (floatx4)0.f; accM[j] = (floatx4)0.f; }

#pragma unroll
    for (int kb = 0; kb < 4; kb++) {
        short8 ay = Ay[kb], ax = Ax[kb];
#pragma unroll
        for (int j = 0; j < 8; j++) {
            int n4 = oh * 8 + j;
            // tile layout: [br:1][n4:4][lane:6] chunks of 16 B
            short8 bc = *(const short8*)(sbuf + (size_t)(n4 * 64 + lane) * 16);
            short8 bm = *(const short8*)(sbuf + 16384 + (size_t)(n4 * 64 + lane) * 16);
            accC[j] = __builtin_amdgcn_mfma_f32_16x16x32_bf16(ay, bc, accC[j], 0, 0, 0);
            accM[j] = __builtin_amdgcn_mfma_f32_16x16x32_bf16(ax, bm, accM[j], 0, 0, 0);
        }
        __syncthreads();                              // all B reads done
        if (kb < 3) {
            const ushort_t* gsrc = wfrag + ((size_t)(kb + 1) * 2048 + w * 512 + lane) * 8;
            char* ldst = sbuf + (size_t)(w * 512) * 16;
#pragma unroll
            for (int i = 0; i < 8; i++)
                gload_lds16(gsrc + i * 64 * 8, ldst + i * 64 * 16);
            __syncthreads();                          // staging visible (vmcnt drained)
        }
    }

    // map-branch bias (before LN3 stats)
#pragma unroll
    for (int j = 0; j < 8; j++) {
        float mb = mbf[(oh * 8 + j) * 16 + l16];
#pragma unroll
        for (int r = 0; r < 4; r++) accM[j][r] += mb;
    }

    // LN partial stats per px (px = quad*4 + r) over this wave's 128 o's
    floatx4 s1 = (floatx4)0.f, q1 = (floatx4)0.f, s2 = (floatx4)0.f, q2 = (floatx4)0.f;
#pragma unroll
    for (int j = 0; j < 8; j++)
#pragma unroll
        for (int r = 0; r < 4; r++) {
            float a = accC[j][r], m = accM[j][r];
            s1[r] += a; q1[r] += a * a;
            s2[r] += m; q2[r] += m * m;
        }
#pragma unroll
    for (int d = 1; d < 16; d <<= 1) {
#pragma unroll
        for (int r = 0; r < 4; r++) {
            s1[r] += __shfl_xor(s1[r], d);
            q1[r] += __shfl_xor(q1[r], d);
            s2[r] += __shfl_xor(s2[r], d);
            q2[r] += __shfl_xor(q2[r], d);
        }
    }

    // exchange partial stats with the pair's other o-half through sbuf (dead)
    float* sstat = (float*)sbuf;
    if (l16 == 0) {
#pragma unroll
        for (int r = 0; r < 4; r++) {
            float* sp = sstat + (((pair * 2 + oh) * 16) + quad * 4 + r) * 4;
            sp[0] = s1[r]; sp[1] = q1[r]; sp[2] = s2[r]; sp[3] = q2[r];
        }
    }
    __syncthreads();

    floatx4 mn1, rs1, mn2, rs2;
#pragma unroll
    for (int r = 0; r < 4; r++) {
        const float* op = sstat + (((pair * 2 + (oh ^ 1)) * 16) + quad * 4 + r) * 4;
        float S1 = s1[r] + op[0], Q1 = q1[r] + op[1];
        float S2 = s2[r] + op[2], Q2 = q2[r] + op[3];
        mn1[r] = S1 * (1.0f / NO);
        rs1[r] = rsqrtf(Q1 * (1.0f / NO) - mn1[r] * mn1[r] + LN_EPS);
        mn2[r] = S2 * (1.0f / NO);
        rs2[r] = rsqrtf(Q2 * (1.0f / NO) - mn2[r] * mn2[r] + LN_EPS);
    }

    // streaming epilogue: per n4, normalize both branches, gelu, direct store
    int batch = pw >> 14;
    int plocal = (pw & 16383) + quad * 4;
#pragma unroll
    for (int j = 0; j < 8; j++) {
        int o = (oh * 8 + j) * 16 + l16;
        float l2w = ln2wf[o], l2b = ln2bf[o];
        float l3w = ln3wf[o], l3b = ln3bf[o];
        float4 gv;
        {
            float v1, v2;
            v1 = (accC[j][0] - mn1[0]) * rs1[0] * l2w + l2b;
            v2 = (accM[j][0] - mn2[0]) * rs2[0] * l3w + l3b;
            gv.x = gelu_f(v1 + v2);
            v1 = (accC[j][1] - mn1[1]) * rs1[1] * l2w + l2b;
            v2 = (accM[j][1] - mn2[1]) * rs2[1] * l3w + l3b;
            gv.y = gelu_f(v1 + v2);
            v1 = (accC[j][2] - mn1[2]) * rs1[2] * l2w + l2b;
            v2 = (accM[j][2] - mn2[2]) * rs2[2] * l3w + l3b;
            gv.z = gelu_f(v1 + v2);
            v1 = (accC[j][3] - mn1[3]) * rs1[3] * l2w + l2b;
            v2 = (accM[j][3] - mn2[3]) * rs2[3] * l3w + l3b;
            gv.w = gelu_f(v1 + v2);
        }
        size_t oi = ((size_t)(batch * NO + o) << 14) + plocal;
        if (isf32) {
            *(float4*)((float*)out + oi) = gv;
        } else {
            uint_t p0 = (uint_t)f2bf(gv.x) | ((uint_t)f2bf(gv.y) << 16);
            uint_t p1 = (uint_t)f2bf(gv.z) | ((uint_t)f2bf(gv.w) << 16);
            *(uint2*)((ushort_t*)out + oi) = make_uint2(p0, p1);
        }
    }
}

// ---------------------------------------------------------------------------
extern "C" void kernel_launch(void* const* d_in, const int* in_sizes, int n_in,
                              void* d_out, int out_size, void* d_ws, size_t ws_size,
                              hipStream_t stream) {
    const void* x      = d_in[0];
    const void* w1     = d_in[1];
    const void* b1     = d_in[2];
    const void* w2     = d_in[3];
    const void* b2     = d_in[4];
    const void* ln1w   = d_in[5];
    const void* ln1b   = d_in[6];
    const void* conv_w = d_in[7];
    const void* ln2w   = d_in[8];
    const void* ln2b   = d_in[9];
    const void* map_w  = d_in[10];
    const void* map_b  = d_in[11];
    const void* ln3w   = d_in[12];
    const void* ln3b   = d_in[13];

    char* ws = (char*)d_ws;
    ushort_t* xT    = (ushort_t*)(ws);                  // 16,777,216 B
    ushort_t* y1    = (ushort_t*)(ws + 16777216);       // 16,777,216 B
    ushort_t* wfrag = (ushort_t*)(ws + 33554432);       // 131,072 B
    ushort_t* w1b   = (ushort_t*)(ws + 33685504);       //   8,192 B
    ushort_t* w2b   = (ushort_t*)(ws + 33693696);       //  25,600 B
    float*    b1f   = (float*)(ws + 33719296);
    float*    b2f   = (float*)(ws + 33719424);
    float*    ln1wf = (float*)(ws + 33721024);
    float*    ln1bf = (float*)(ws + 33721536);
    float*    mbf   = (float*)(ws + 33722048);
    float*    ln2wf = (float*)(ws + 33723072);
    float*    ln2bf = (float*)(ws + 33724096);
    float*    ln3wf = (float*)(ws + 33725120);
    float*    ln3bf = (float*)(ws + 33726144);
    const size_t NEED_SMALL = 33727184;

    if (ws_size < NEED_SMALL) {
        int nwords = out_size / 2;
        ksentinel<<<(nwords + 255) / 256, 256, 0, stream>>>((uint_t*)d_out, nwords);
        return;
    }

    kprepfrag<<<160, 256, 0, stream>>>(x, w1, w2, b1, b2, ln1w, ln1b,
                                       ln2w, ln2b, map_b, ln3w, ln3b,
                                       conv_w, map_w,
                                       w1b, w2b, b1f, b2f, ln1wf, ln1bf,
                                       ln2wf, ln2bf, mbf, ln3wf, ln3bf, wfrag);
    ktrans<<<dim3(8, 128, 4), 256, 0, stream>>>(x, xT);
    k1f<<<1024, 512, 0, stream>>>(xT, w1b, b1f, w2b, b2f, ln1wf, ln1bf, y1);
    k23<<<NPIX / 32, 256, 0, stream>>>(x, y1, xT, wfrag, mbf,
                                       ln2wf, ln2bf, ln3wf, ln3bf, d_out);
}

// Round 11
// 204.733 us; speedup vs baseline: 1.0916x; 1.0078x over previous
//
#include <hip/hip_runtime.h>

typedef unsigned short ushort_t;
typedef unsigned int uint_t;

#define NB 4
#define NC 128
#define NH 128
#define NW 128
#define NPIX 65536   // NB*NH*NW
#define NMID 32
#define NKK 49
#define NK 392
#define NKP 400      // NK padded to 25 n-tiles of 16
#define NO 256
#define LN_EPS 1e-6f

typedef __attribute__((ext_vector_type(8))) short short8;
typedef __attribute__((ext_vector_type(4))) float floatx4;

__device__ __forceinline__ float bf2f(ushort_t u) {
    union { uint_t i; float f; } v; v.i = ((uint_t)u) << 16; return v.f;
}
__device__ __forceinline__ float bf2f_lo(uint_t u) {
    union { uint_t i; float f; } v; v.i = u << 16; return v.f;
}
__device__ __forceinline__ float bf2f_hi(uint_t u) {
    union { uint_t i; float f; } v; v.i = u & 0xffff0000u; return v.f;
}
__device__ __forceinline__ ushort_t f2bf(float f) {
    union { float f; uint_t i; } v; v.f = f;
    uint_t x = v.i;
    uint_t r = (x + 0x7FFFu + ((x >> 16) & 1u)) >> 16;
    return (ushort_t)r;
}
__device__ __forceinline__ float gelu_f(float x) {
    return 0.5f * x * (1.0f + erff(x * 0.70710678118654752f));
}
__device__ __forceinline__ float ldin(const void* p, int i, int isf32) {
    return isf32 ? ((const float*)p)[i] : bf2f(((const ushort_t*)p)[i]);
}
// global -> LDS direct DMA, 16B per lane; LDS dest = uniform base + lane*16
__device__ __forceinline__ void gload_lds16(const void* g, void* l) {
    __builtin_amdgcn_global_load_lds(
        (const __attribute__((address_space(1))) void*)g,
        (__attribute__((address_space(3))) void*)l, 16, 0, 0);
}

// ---------------------------------------------------------------------------
// Per-block dtype sniff (in_sizes are ELEMENT counts — r8 post-mortem — so
// runtime sniffing is required). One wave computes, broadcast via LDS.
// ---------------------------------------------------------------------------
__device__ __forceinline__ int sniff_isf32(const void* x, int* lf) {
    int t = threadIdx.x;
    if (t < 64) {
        const uint_t* xw = (const uint_t*)x;
        int cnt = 0;
#pragma unroll
        for (int j = 0; j < 8; j++) {
            uint_t wv = xw[t * 8 + j];
            uint_t e = (wv >> 7) & 0xffu;
            if (e >= 110u && e <= 135u) cnt++;
        }
#pragma unroll
        for (int d = 1; d < 64; d <<= 1) cnt += __shfl_xor(cnt, d);
        if (t == 0) *lf = (cnt < 256) ? 1 : 0;
    }
    __syncthreads();
    return *lf;
}

__global__ void ksentinel(uint_t* __restrict__ out, int nwords) {
    int i = blockIdx.x * 256 + threadIdx.x;
    if (i < nwords) out[i] = 0x40004000u;
}

// ---------------------------------------------------------------------------
// K0a v2: transpose x (B,C,H,W) -> xT (B,H,W,C) bf16, VECTORIZED.
// r10 version did 8 scalar u16 stores + 8 scalar loads per thread (G13
// common-mistake). Now: tile[32][64] (128B rows); write phase is per-wave
// CONTIGUOUS b128 (byte = 16*t — the k23-proven zero-conflict pattern);
// read phase is row-broadcast u16 (all lanes same row, pair-share words);
// one uint4 global store per thread (4 lanes = 64B per pixel).
// grid (8,128,4), block 256.
// ---------------------------------------------------------------------------
__global__ __launch_bounds__(256) void ktrans(const void* __restrict__ x,
                                              ushort_t* __restrict__ xT) {
    __shared__ __align__(16) ushort_t tile[32][64];
    __shared__ int lf;
    int isf32 = sniff_isf32(x, &lf);
    int b = blockIdx.z, h = blockIdx.y;
    int wchunk = blockIdx.x & 1, cchunk = blockIdx.x >> 1;
    int w0 = wchunk << 6, c0 = cchunk << 5;
    int t = threadIdx.x;

    {
        int cc = t >> 3, wseg = t & 7;   // 32 c-rows x 8 w-segments of 8
        size_t idx = (size_t)((b * NC + c0 + cc) * NH + h) * NW + w0 + wseg * 8;
        uint4 pk;
        if (isf32) {
            float4 f0 = *(const float4*)((const float*)x + idx);
            float4 f1 = *(const float4*)((const float*)x + idx + 4);
            pk.x = (uint_t)f2bf(f0.x) | ((uint_t)f2bf(f0.y) << 16);
            pk.y = (uint_t)f2bf(f0.z) | ((uint_t)f2bf(f0.w) << 16);
            pk.z = (uint_t)f2bf(f1.x) | ((uint_t)f2bf(f1.y) << 16);
            pk.w = (uint_t)f2bf(f1.z) | ((uint_t)f2bf(f1.w) << 16);
        } else {
            pk = *(const uint4*)((const ushort_t*)x + idx);
        }
        *(uint4*)&tile[cc][wseg * 8] = pk;   // byte = 16*t: wave-contiguous
    }
    __syncthreads();

    int wx = t & 63, cq = t >> 6;            // 64 pixels x 4 c-quarters of 8
    ushort_t o[8];
#pragma unroll
    for (int j = 0; j < 8; j++) o[j] = tile[cq * 8 + j][wx];
    *(uint4*)&xT[((size_t)((b * NH + h) * NW) + w0 + wx) * NC + c0 + cq * 8]
        = *(uint4*)o;
}

// ---------------------------------------------------------------------------
// KPREPFRAG: merged param-prep + conv/map fragment repack. Local sniff.
// Blocks [0,128): kprep body. Blocks [128,160): kfrag body.
// kfrag chunk id cid = [kb:2][br:1][n4:4][lane:6], chunk = 8 bf16 = 16 B;
// each kb-tile (32 KB) contiguous -> linear global_load_lds target in k23.
// ---------------------------------------------------------------------------
__global__ __launch_bounds__(256) void kprepfrag(const void* x,
                                                 const void* w1, const void* w2,
                                                 const void* b1, const void* b2,
                                                 const void* ln1w, const void* ln1b,
                                                 const void* ln2w, const void* ln2b,
                                                 const void* map_b,
                                                 const void* ln3w, const void* ln3b,
                                                 const void* conv_w, const void* map_w,
                                                 ushort_t* __restrict__ w1b,
                                                 ushort_t* __restrict__ w2b,
                                                 float* __restrict__ b1f,
                                                 float* __restrict__ b2f,
                                                 float* __restrict__ ln1wf,
                                                 float* __restrict__ ln1bf,
                                                 float* __restrict__ ln2wf,
                                                 float* __restrict__ ln2bf,
                                                 float* __restrict__ mbf,
                                                 float* __restrict__ ln3wf,
                                                 float* __restrict__ ln3bf,
                                                 ushort_t* __restrict__ wfrag) {
    __shared__ int lf;
    int isf32 = sniff_isf32(x, &lf);
    int bid = blockIdx.x;
    if (bid < 128) {
        int i = bid * 256 + threadIdx.x;
        if (i < NMID * NC) w1b[i] = f2bf(ldin(w1, i, isf32));
        if (i < NKP * NMID) w2b[i] = (i < NK * NMID) ? f2bf(ldin(w2, i, isf32))
                                                     : (ushort_t)0;
        if (i < NMID) b1f[i] = ldin(b1, i, isf32);
        if (i < NKP)  b2f[i] = (i < NK) ? ldin(b2, i, isf32) : 0.f;
        if (i < NC) { ln1wf[i] = ldin(ln1w, i, isf32); ln1bf[i] = ldin(ln1b, i, isf32); }
        if (i < NO) {
            ln2wf[i] = ldin(ln2w, i, isf32); ln2bf[i] = ldin(ln2b, i, isf32);
            mbf[i]   = ldin(map_b, i, isf32);
            ln3wf[i] = ldin(ln3w, i, isf32); ln3bf[i] = ldin(ln3b, i, isf32);
        }
    } else {
        int cid = (bid - 128) * 256 + threadIdx.x;   // [0, 8192)
        int lane = cid & 63, n4 = (cid >> 6) & 15, br = (cid >> 10) & 1, kb = cid >> 11;
        int o = n4 * 16 + (lane & 15);
        int ch0 = kb * 32 + (lane >> 4) * 8;
        const void* src = br ? map_w : conv_w;
        ushort_t* dst = wfrag + (size_t)cid * 8;
#pragma unroll
        for (int j = 0; j < 8; j++)
            dst[j] = f2bf(ldin(src, o * NC + ch0 + j, isf32));
    }
}

// ---------------------------------------------------------------------------
// K1F v3: v2 + oct-XOR bank-deconflict on the x8 halo (r10 counters: tap
// reads were EXACTLY 8-way serialized — 6.42M extra cycles = 8.0 x 802,816
// b128 reads; start phases 4*(14*py+pxx) mod 32 alias 8 lanes per 4-bank
// span). Swizzle: element (oct, hp) stored at oct' = oct ^ ((hp>>3)&7);
// reads use s = (xa>>3)&7. Within each colliding class (same xa mod 8,
// distinct xa>>3) the 20*oct' term maps 8 lanes to 8 distinct phases
// ({0,20,8,28,16,4,24,12}). Bijective; staging writes stay conflict-free.
// Block 512, grid 1024.
// ---------------------------------------------------------------------------
__global__ __launch_bounds__(512) void k1f(const ushort_t* __restrict__ xT,
                                           const ushort_t* __restrict__ w1b,
                                           const float* __restrict__ b1f,
                                           const ushort_t* __restrict__ w2b,
                                           const float* __restrict__ b2f,
                                           const float* __restrict__ ln1wf,
                                           const float* __restrict__ ln1bf,
                                           ushort_t* __restrict__ y1) {
    __shared__ __align__(16) char smem[52800];   // wkstage, then x8/sred
    __shared__ ushort_t midbuf[64 * 32];
    ushort_t* wkstage = (ushort_t*)smem;
    uint4*    x8      = (uint4*)smem;
    float*    sred    = (float*)smem;

    int t = threadIdx.x;
    int lane = t & 63;
    int w = __builtin_amdgcn_readfirstlane(t >> 6);   // 0..7
    int l16 = lane & 15, quad = lane >> 4;
    int tileid = blockIdx.x;
    int tilex = tileid & 15, tiley = (tileid >> 4) & 15, b = tileid >> 8;
    int h0 = tiley * 8, w0 = tilex * 8;
    int w4 = w & 3;

    // ---- Phase A1: mid = relu(w1 @ x + b1), waves 0..3 (16 px each) ----
    if (w < 4) {
        int lpx = 16 * w + l16;
        int py = lpx >> 3, pxx = lpx & 7;
        const ushort_t* abase = xT + (size_t)((b * NH + h0 + py) * NW + w0 + pxx) * NC + quad * 8;
        floatx4 am0 = (floatx4)0.f, am1 = (floatx4)0.f;
#pragma unroll
        for (int kb = 0; kb < 4; kb++) {
            short8 a   = *(const short8*)(abase + kb * 32);
            short8 b0  = *(const short8*)(w1b + (l16) * NC + kb * 32 + quad * 8);
            short8 b1v = *(const short8*)(w1b + (16 + l16) * NC + kb * 32 + quad * 8);
            am0 = __builtin_amdgcn_mfma_f32_16x16x32_bf16(a, b0, am0, 0, 0, 0);
            am1 = __builtin_amdgcn_mfma_f32_16x16x32_bf16(a, b1v, am1, 0, 0, 0);
        }
        float bia0 = b1f[l16], bia1 = b1f[16 + l16];
#pragma unroll
        for (int r = 0; r < 4; r++) {
            int m = 16 * w + quad * 4 + r;
            midbuf[m * 32 + l16]      = f2bf(fmaxf(am0[r] + bia0, 0.f));
            midbuf[m * 32 + 16 + l16] = f2bf(fmaxf(am1[r] + bia1, 0.f));
        }
    }
    __syncthreads();

    // ---- Phase A2: wk = w2 @ mid + b2 -> wkstage[n][px] (8 waves) ----
    {
        short8 aM = *(const short8*)(midbuf + (16 * w4 + l16) * 32 + quad * 8);
        int nt0 = (w < 4) ? 0 : 13;
        int nt1 = (w < 4) ? 13 : 25;
        for (int nt = nt0; nt < nt1; nt++) {
            int n = nt * 16 + l16;
            short8 bw = *(const short8*)(w2b + n * 32 + quad * 8);
            floatx4 c = __builtin_amdgcn_mfma_f32_16x16x32_bf16(aM, bw, (floatx4)0.f, 0, 0, 0);
            float bias = b2f[n];
#pragma unroll
            for (int r = 0; r < 4; r++)
                wkstage[n * 66 + 16 * w4 + quad * 4 + r] = f2bf(c[r] + bias);
        }
    }
    __syncthreads();

    // ---- wkp preload: lane = px, wave w = group w. Rows are 64 consecutive
    // ushorts -> conflict-free. 25 packed regs per lane (k1b's layout). ----
    uint_t wkp[25];
#pragma unroll
    for (int j = 0; j < 24; j++) {
        uint_t lo = wkstage[(w * NKK + 2 * j) * 66 + lane];
        uint_t hi = wkstage[(w * NKK + 2 * j + 1) * 66 + lane];
        wkp[j] = lo | (hi << 16);
    }
    wkp[24] = wkstage[(w * NKK + 48) * 66 + lane];
    __syncthreads();        // all wk reads complete before LDS reuse

    // ---- Halo staging into x8 (overwrites wkstage; oct-XOR swizzled) ----
    for (int it = 0; it < 7; it++) {
        int idx = it * 512 + t;
        if (idx < 3136) {
            int oct = idx & 15, hp = idx >> 4;
            int hy = hp / 14, hx = hp - hy * 14;
            int gh = h0 + hy - 3, gw = w0 + hx - 3;
            uint4 v = make_uint4(0u, 0u, 0u, 0u);
            if ((unsigned)gh < (unsigned)NH && (unsigned)gw < (unsigned)NW) {
                v = *(const uint4*)&xT[(size_t)((b * NH + gh) * NW + gw) * NC + 8 * oct];
            }
            x8[(oct ^ ((hp >> 3) & 7)) * 197 + hp] = v;
        }
    }
    __syncthreads();

    // ---- Phase B: involution from LDS (swizzled reads) ----
    int py = lane >> 3, pxx = lane & 7;
    int base0 = py * 14 + pxx;
    float a[16];
#pragma unroll
    for (int j = 0; j < 16; j++) a[j] = 0.f;

#pragma unroll
    for (int tap = 0; tap < NKK; tap++) {
        float wkf = (tap & 1) ? bf2f((ushort_t)(wkp[tap >> 1] >> 16))
                              : bf2f((ushort_t)(wkp[tap >> 1] & 0xffffu));
        int xa = base0 + (tap / 7) * 14 + (tap % 7);
        int s = (xa >> 3) & 7;
        uint4 u0 = x8[((2 * w) ^ s) * 197 + xa];
        uint4 u1 = x8[((2 * w + 1) ^ s) * 197 + xa];
        a[0]  = fmaf(wkf, bf2f_lo(u0.x), a[0]);
        a[1]  = fmaf(wkf, bf2f_hi(u0.x), a[1]);
        a[2]  = fmaf(wkf, bf2f_lo(u0.y), a[2]);
        a[3]  = fmaf(wkf, bf2f_hi(u0.y), a[3]);
        a[4]  = fmaf(wkf, bf2f_lo(u0.z), a[4]);
        a[5]  = fmaf(wkf, bf2f_hi(u0.z), a[5]);
        a[6]  = fmaf(wkf, bf2f_lo(u0.w), a[6]);
        a[7]  = fmaf(wkf, bf2f_hi(u0.w), a[7]);
        a[8]  = fmaf(wkf, bf2f_lo(u1.x), a[8]);
        a[9]  = fmaf(wkf, bf2f_hi(u1.x), a[9]);
        a[10] = fmaf(wkf, bf2f_lo(u1.y), a[10]);
        a[11] = fmaf(wkf, bf2f_hi(u1.y), a[11]);
        a[12] = fmaf(wkf, bf2f_lo(u1.z), a[12]);
        a[13] = fmaf(wkf, bf2f_hi(u1.z), a[13]);
        a[14] = fmaf(wkf, bf2f_lo(u1.w), a[14]);
        a[15] = fmaf(wkf, bf2f_hi(u1.w), a[15]);
    }
    __syncthreads();

    // ---- LN1 over 128 ch (block-wide sred reduction) ----
    float s = 0.f, sq = 0.f;
#pragma unroll
    for (int j = 0; j < 16; j++) { s += a[j]; sq += a[j] * a[j]; }
    sred[(w * 64 + lane) * 2]     = s;
    sred[(w * 64 + lane) * 2 + 1] = sq;
    __syncthreads();
    float ts = 0.f, tq = 0.f;
#pragma unroll
    for (int r = 0; r < 8; r++) {
        ts += sred[(r * 64 + lane) * 2];
        tq += sred[(r * 64 + lane) * 2 + 1];
    }
    float mean = ts * (1.0f / NC);
    float var = tq * (1.0f / NC) - mean * mean;
    float rstd = rsqrtf(var + LN_EPS);

    int p = (b * NH + h0 + py) * NW + w0 + pxx;
    uint_t pk[8];
#pragma unroll
    for (int j = 0; j < 8; j++) {
        int c0 = 16 * w + 2 * j;
        float g0 = gelu_f((a[2 * j] - mean) * rstd * ln1wf[c0] + ln1bf[c0]);
        float g1 = gelu_f((a[2 * j + 1] - mean) * rstd * ln1wf[c0 + 1] + ln1bf[c0 + 1]);
        pk[j] = (uint_t)f2bf(g0) | ((uint_t)f2bf(g1) << 16);
    }
    uint4* dst = (uint4*)(y1 + (size_t)p * NC + 16 * w);
    dst[0] = make_uint4(pk[0], pk[1], pk[2], pk[3]);
    dst[1] = make_uint4(pk[4], pk[5], pk[6], pk[7]);
}

// ---------------------------------------------------------------------------
// K23 v10 (unchanged). o-half split wave pairs; LDS-staged B via
// global_load_lds; streaming epilogue; 64 VGPR + 64 AGPR, no spill.
// grid 2048, block 256.
// ---------------------------------------------------------------------------
__global__ __launch_bounds__(256, 4) void k23(const void* __restrict__ x,
                                              const ushort_t* __restrict__ y1,
                                              const ushort_t* __restrict__ xT,
                                              const ushort_t* __restrict__ wfrag,
                                              const float* __restrict__ mbf,
                                              const float* __restrict__ ln2wf,
                                              const float* __restrict__ ln2bf,
                                              const float* __restrict__ ln3wf,
                                              const float* __restrict__ ln3bf,
                                              void* __restrict__ out) {
    __shared__ __align__(16) char sbuf[32768];   // B stage, reused for stats
    __shared__ int lf;
    int isf32 = sniff_isf32(x, &lf);

    int t = threadIdx.x;
    int lane = t & 63;
    int w = __builtin_amdgcn_readfirstlane(t >> 6);   // 0..3
    int quad = lane >> 4, l16 = lane & 15;
    int pair = w >> 1;                                // 0..1 -> px group
    int oh   = w & 1;                                 // 0..1 -> o-half (128 o's)

    int P0 = blockIdx.x * 32;
    int pw = P0 + pair * 16;                          // this wave's first pixel
    const ushort_t* aYp = y1 + (size_t)(pw + l16) * NC + quad * 8;
    const ushort_t* aXp = xT + (size_t)(pw + l16) * NC + quad * 8;

    // stage kb=0 B-tile (32KB): wave w covers chunks [w*512, w*512+512)
    {
        const ushort_t* gsrc = wfrag + (size_t)(w * 512 + lane) * 8;
        char* ldst = sbuf + (size_t)(w * 512) * 16;
#pragma unroll
        for (int i = 0; i < 8; i++)
            gload_lds16(gsrc + i * 64 * 8, ldst + i * 64 * 16);
    }
    // A operands (both branches) for all 4 k-blocks, hoisted to registers
    short8 Ay[4], Ax[4];
#pragma unroll
    for (int kb = 0; kb < 4; kb++) {
        Ay[kb] = *(const short8*)(aYp + kb * 32);
        Ax[kb] = *(const short8*)(aXp + kb * 32);
    }
    __syncthreads();

    floatx4 accC[8], accM[8];
#pragma unroll
    for (int j = 0; j < 8; j++) { accC[j] = (floatx4)0.f; accM[j] = (floatx4)0.f; }

#pragma unroll
    for (int kb = 0; kb < 4; kb++) {
        short8 ay = Ay[kb], ax = Ax[kb];
#pragma unroll
        for (int j = 0; j < 8; j++) {
            int n4 = oh * 8 + j;
            // tile layout: [br:1][n4:4][lane:6] chunks of 16 B
            short8 bc = *(const short8*)(sbuf + (size_t)(n4 * 64 + lane) * 16);
            short8 bm = *(const short8*)(sbuf + 16384 + (size_t)(n4 * 64 + lane) * 16);
            accC[j] = __builtin_amdgcn_mfma_f32_16x16x32_bf16(ay, bc, accC[j], 0, 0, 0);
            accM[j] = __builtin_amdgcn_mfma_f32_16x16x32_bf16(ax, bm, accM[j], 0, 0, 0);
        }
        __syncthreads();                              // all B reads done
        if (kb < 3) {
            const ushort_t* gsrc = wfrag + ((size_t)(kb + 1) * 2048 + w * 512 + lane) * 8;
            char* ldst = sbuf + (size_t)(w * 512) * 16;
#pragma unroll
            for (int i = 0; i < 8; i++)
                gload_lds16(gsrc + i * 64 * 8, ldst + i * 64 * 16);
            __syncthreads();                          // staging visible (vmcnt drained)
        }
    }

    // map-branch bias (before LN3 stats)
#pragma unroll
    for (int j = 0; j < 8; j++) {
        float mb = mbf[(oh * 8 + j) * 16 + l16];
#pragma unroll
        for (int r = 0; r < 4; r++) accM[j][r] += mb;
    }

    // LN partial stats per px (px = quad*4 + r) over this wave's 128 o's
    floatx4 s1 = (floatx4)0.f, q1 = (floatx4)0.f, s2 = (floatx4)0.f, q2 = (floatx4)0.f;
#pragma unroll
    for (int j = 0; j < 8; j++)
#pragma unroll
        for (int r = 0; r < 4; r++) {
            float a = accC[j][r], m = accM[j][r];
            s1[r] += a; q1[r] += a * a;
            s2[r] += m; q2[r] += m * m;
        }
#pragma unroll
    for (int d = 1; d < 16; d <<= 1) {
#pragma unroll
        for (int r = 0; r < 4; r++) {
            s1[r] += __shfl_xor(s1[r], d);
            q1[r] += __shfl_xor(q1[r], d);
            s2[r] += __shfl_xor(s2[r], d);
            q2[r] += __shfl_xor(q2[r], d);
        }
    }

    // exchange partial stats with the pair's other o-half through sbuf (dead)
    float* sstat = (float*)sbuf;
    if (l16 == 0) {
#pragma unroll
        for (int r = 0; r < 4; r++) {
            float* sp = sstat + (((pair * 2 + oh) * 16) + quad * 4 + r) * 4;
            sp[0] = s1[r]; sp[1] = q1[r]; sp[2] = s2[r]; sp[3] = q2[r];
        }
    }
    __syncthreads();

    floatx4 mn1, rs1, mn2, rs2;
#pragma unroll
    for (int r = 0; r < 4; r++) {
        const float* op = sstat + (((pair * 2 + (oh ^ 1)) * 16) + quad * 4 + r) * 4;
        float S1 = s1[r] + op[0], Q1 = q1[r] + op[1];
        float S2 = s2[r] + op[2], Q2 = q2[r] + op[3];
        mn1[r] = S1 * (1.0f / NO);
        rs1[r] = rsqrtf(Q1 * (1.0f / NO) - mn1[r] * mn1[r] + LN_EPS);
        mn2[r] = S2 * (1.0f / NO);
        rs2[r] = rsqrtf(Q2 * (1.0f / NO) - mn2[r] * mn2[r] + LN_EPS);
    }

    // streaming epilogue: per n4, normalize both branches, gelu, direct store
    int batch = pw >> 14;
    int plocal = (pw & 16383) + quad * 4;
#pragma unroll
    for (int j = 0; j < 8; j++) {
        int o = (oh * 8 + j) * 16 + l16;
        float l2w = ln2wf[o], l2b = ln2bf[o];
        float l3w = ln3wf[o], l3b = ln3bf[o];
        float4 gv;
        {
            float v1, v2;
            v1 = (accC[j][0] - mn1[0]) * rs1[0] * l2w + l2b;
            v2 = (accM[j][0] - mn2[0]) * rs2[0] * l3w + l3b;
            gv.x = gelu_f(v1 + v2);
            v1 = (accC[j][1] - mn1[1]) * rs1[1] * l2w + l2b;
            v2 = (accM[j][1] - mn2[1]) * rs2[1] * l3w + l3b;
            gv.y = gelu_f(v1 + v2);
            v1 = (accC[j][2] - mn1[2]) * rs1[2] * l2w + l2b;
            v2 = (accM[j][2] - mn2[2]) * rs2[2] * l3w + l3b;
            gv.z = gelu_f(v1 + v2);
            v1 = (accC[j][3] - mn1[3]) * rs1[3] * l2w + l2b;
            v2 = (accM[j][3] - mn2[3]) * rs2[3] * l3w + l3b;
            gv.w = gelu_f(v1 + v2);
        }
        size_t oi = ((size_t)(batch * NO + o) << 14) + plocal;
        if (isf32) {
            *(float4*)((float*)out + oi) = gv;
        } else {
            uint_t p0 = (uint_t)f2bf(gv.x) | ((uint_t)f2bf(gv.y) << 16);
            uint_t p1 = (uint_t)f2bf(gv.z) | ((uint_t)f2bf(gv.w) << 16);
            *(uint2*)((ushort_t*)out + oi) = make_uint2(p0, p1);
        }
    }
}

// ---------------------------------------------------------------------------
extern "C" void kernel_launch(void* const* d_in, const int* in_sizes, int n_in,
                              void* d_out, int out_size, void* d_ws, size_t ws_size,
                              hipStream_t stream) {
    const void* x      = d_in[0];
    const void* w1     = d_in[1];
    const void* b1     = d_in[2];
    const void* w2     = d_in[3];
    const void* b2     = d_in[4];
    const void* ln1w   = d_in[5];
    const void* ln1b   = d_in[6];
    const void* conv_w = d_in[7];
    const void* ln2w   = d_in[8];
    const void* ln2b   = d_in[9];
    const void* map_w  = d_in[10];
    const void* map_b  = d_in[11];
    const void* ln3w   = d_in[12];
    const void* ln3b   = d_in[13];

    char* ws = (char*)d_ws;
    ushort_t* xT    = (ushort_t*)(ws);                  // 16,777,216 B
    ushort_t* y1    = (ushort_t*)(ws + 16777216);       // 16,777,216 B
    ushort_t* wfrag = (ushort_t*)(ws + 33554432);       // 131,072 B
    ushort_t* w1b   = (ushort_t*)(ws + 33685504);       //   8,192 B
    ushort_t* w2b   = (ushort_t*)(ws + 33693696);       //  25,600 B
    float*    b1f   = (float*)(ws + 33719296);
    float*    b2f   = (float*)(ws + 33719424);
    float*    ln1wf = (float*)(ws + 33721024);
    float*    ln1bf = (float*)(ws + 33721536);
    float*    mbf   = (float*)(ws + 33722048);
    float*    ln2wf = (float*)(ws + 33723072);
    float*    ln2bf = (float*)(ws + 33724096);
    float*    ln3wf = (float*)(ws + 33725120);
    float*    ln3bf = (float*)(ws + 33726144);
    const size_t NEED_SMALL = 33727184;

    if (ws_size < NEED_SMALL) {
        int nwords = out_size / 2;
        ksentinel<<<(nwords + 255) / 256, 256, 0, stream>>>((uint_t*)d_out, nwords);
        return;
    }

    kprepfrag<<<160, 256, 0, stream>>>(x, w1, w2, b1, b2, ln1w, ln1b,
                                       ln2w, ln2b, map_b, ln3w, ln3b,
                                       conv_w, map_w,
                                       w1b, w2b, b1f, b2f, ln1wf, ln1bf,
                                       ln2wf, ln2bf, mbf, ln3wf, ln3bf, wfrag);
    ktrans<<<dim3(8, 128, 4), 256, 0, stream>>>(x, xT);
    k1f<<<1024, 512, 0, stream>>>(xT, w1b, b1f, w2b, b2f, ln1wf, ln1bf, y1);
    k23<<<NPIX / 32, 256, 0, stream>>>(x, y1, xT, wfrag, mbf,
                                       ln2wf, ln2bf, ln3wf, ln3bf, d_out);
}

// Round 12
// 203.021 us; speedup vs baseline: 1.1008x; 1.0084x over previous
//
#include <hip/hip_runtime.h>

typedef unsigned short ushort_t;
typedef unsigned int uint_t;

#define NB 4
#define NC 128
#define NH 128
#define NW 128
#define NPIX 65536   // NB*NH*NW
#define NMID 32
#define NKK 49
#define NK 392
#define NKP 400      // NK padded to 25 n-tiles of 16
#define NO 256
#define LN_EPS 1e-6f

typedef __attribute__((ext_vector_type(8))) short short8;
typedef __attribute__((ext_vector_type(4))) float floatx4;

__device__ __forceinline__ float bf2f(ushort_t u) {
    union { uint_t i; float f; } v; v.i = ((uint_t)u) << 16; return v.f;
}
__device__ __forceinline__ float bf2f_lo(uint_t u) {
    union { uint_t i; float f; } v; v.i = u << 16; return v.f;
}
__device__ __forceinline__ float bf2f_hi(uint_t u) {
    union { uint_t i; float f; } v; v.i = u & 0xffff0000u; return v.f;
}
__device__ __forceinline__ ushort_t f2bf(float f) {
    union { float f; uint_t i; } v; v.f = f;
    uint_t x = v.i;
    uint_t r = (x + 0x7FFFu + ((x >> 16) & 1u)) >> 16;
    return (ushort_t)r;
}
__device__ __forceinline__ float gelu_f(float x) {
    return 0.5f * x * (1.0f + erff(x * 0.70710678118654752f));
}
__device__ __forceinline__ float ldin(const void* p, int i, int isf32) {
    return isf32 ? ((const float*)p)[i] : bf2f(((const ushort_t*)p)[i]);
}
// global -> LDS direct DMA, 16B per lane; LDS dest = uniform base + lane*16
__device__ __forceinline__ void gload_lds16(const void* g, void* l) {
    __builtin_amdgcn_global_load_lds(
        (const __attribute__((address_space(1))) void*)g,
        (__attribute__((address_space(3))) void*)l, 16, 0, 0);
}

// ---------------------------------------------------------------------------
// Per-block dtype sniff (in_sizes are ELEMENT counts — r8 post-mortem — so
// runtime sniffing is required). One wave computes, broadcast via LDS.
// ---------------------------------------------------------------------------
__device__ __forceinline__ int sniff_isf32(const void* x, int* lf) {
    int t = threadIdx.x;
    if (t < 64) {
        const uint_t* xw = (const uint_t*)x;
        int cnt = 0;
#pragma unroll
        for (int j = 0; j < 8; j++) {
            uint_t wv = xw[t * 8 + j];
            uint_t e = (wv >> 7) & 0xffu;
            if (e >= 110u && e <= 135u) cnt++;
        }
#pragma unroll
        for (int d = 1; d < 64; d <<= 1) cnt += __shfl_xor(cnt, d);
        if (t == 0) *lf = (cnt < 256) ? 1 : 0;
    }
    __syncthreads();
    return *lf;
}

__global__ void ksentinel(uint_t* __restrict__ out, int nwords) {
    int i = blockIdx.x * 256 + threadIdx.x;
    if (i < nwords) out[i] = 0x40004000u;
}

// ---------------------------------------------------------------------------
// K0a v3: transpose x (B,C,H,W) -> xT (B,H,W,C) bf16, both sides coalesced.
// r11 defect: store phase wrote 16B/lane at 256B lane stride (partial cache
// lines, ~1/4 write efficiency). v3: tile[32][72] (rows 16B-aligned);
// read = 1 vector load + 1 aligned uint4 LDS write per thread (8 balanced
// start-phases = minimal for b128); write = thread (px=t>>2, seg=t&3) gathers
// 8 u16 (dword-broadcast pairs, ~4-way, cheap) -> ONE uint4 store; 4 lanes
// form a dense 64B granule, wave = 16 dense segments. grid (8,128,4), 256.
// ---------------------------------------------------------------------------
__global__ __launch_bounds__(256) void ktrans(const void* __restrict__ x,
                                              ushort_t* __restrict__ xT) {
    __shared__ __align__(16) ushort_t tile[32][72];
    __shared__ int lf;
    int isf32 = sniff_isf32(x, &lf);
    int b = blockIdx.z, h = blockIdx.y;
    int wchunk = blockIdx.x & 1, cchunk = blockIdx.x >> 1;
    int w0 = wchunk << 6, c0 = cchunk << 5;
    int t = threadIdx.x;

    {
        int cc = t >> 3, wseg = t & 7;   // 32 c-rows x 8 w-segments of 8
        size_t idx = (size_t)((b * NC + c0 + cc) * NH + h) * NW + w0 + wseg * 8;
        uint4 pk;
        if (isf32) {
            float4 f0 = *(const float4*)((const float*)x + idx);
            float4 f1 = *(const float4*)((const float*)x + idx + 4);
            pk.x = (uint_t)f2bf(f0.x) | ((uint_t)f2bf(f0.y) << 16);
            pk.y = (uint_t)f2bf(f0.z) | ((uint_t)f2bf(f0.w) << 16);
            pk.z = (uint_t)f2bf(f1.x) | ((uint_t)f2bf(f1.y) << 16);
            pk.w = (uint_t)f2bf(f1.z) | ((uint_t)f2bf(f1.w) << 16);
        } else {
            pk = *(const uint4*)((const ushort_t*)x + idx);
        }
        *(uint4*)&tile[cc][wseg * 8] = pk;
    }
    __syncthreads();

    int px = t >> 2, seg = t & 3;        // 64 pixels x 4 ch-segments of 8
    ushort_t o[8];
#pragma unroll
    for (int j = 0; j < 8; j++) o[j] = tile[seg * 8 + j][px];
    *(uint4*)&xT[((size_t)((b * NH + h) * NW) + w0 + px) * NC + c0 + seg * 8]
        = *(uint4*)o;
}

// ---------------------------------------------------------------------------
// KPREPFRAG: merged param-prep + conv/map fragment repack. Local sniff.
// Blocks [0,128): kprep body. Blocks [128,160): kfrag body.
// kfrag chunk id cid = [kb:2][br:1][n4:4][lane:6], chunk = 8 bf16 = 16 B;
// each kb-tile (32 KB) contiguous -> linear global_load_lds target in k23.
// ---------------------------------------------------------------------------
__global__ __launch_bounds__(256) void kprepfrag(const void* x,
                                                 const void* w1, const void* w2,
                                                 const void* b1, const void* b2,
                                                 const void* ln1w, const void* ln1b,
                                                 const void* ln2w, const void* ln2b,
                                                 const void* map_b,
                                                 const void* ln3w, const void* ln3b,
                                                 const void* conv_w, const void* map_w,
                                                 ushort_t* __restrict__ w1b,
                                                 ushort_t* __restrict__ w2b,
                                                 float* __restrict__ b1f,
                                                 float* __restrict__ b2f,
                                                 float* __restrict__ ln1wf,
                                                 float* __restrict__ ln1bf,
                                                 float* __restrict__ ln2wf,
                                                 float* __restrict__ ln2bf,
                                                 float* __restrict__ mbf,
                                                 float* __restrict__ ln3wf,
                                                 float* __restrict__ ln3bf,
                                                 ushort_t* __restrict__ wfrag) {
    __shared__ int lf;
    int isf32 = sniff_isf32(x, &lf);
    int bid = blockIdx.x;
    if (bid < 128) {
        int i = bid * 256 + threadIdx.x;
        if (i < NMID * NC) w1b[i] = f2bf(ldin(w1, i, isf32));
        if (i < NKP * NMID) w2b[i] = (i < NK * NMID) ? f2bf(ldin(w2, i, isf32))
                                                     : (ushort_t)0;
        if (i < NMID) b1f[i] = ldin(b1, i, isf32);
        if (i < NKP)  b2f[i] = (i < NK) ? ldin(b2, i, isf32) : 0.f;
        if (i < NC) { ln1wf[i] = ldin(ln1w, i, isf32); ln1bf[i] = ldin(ln1b, i, isf32); }
        if (i < NO) {
            ln2wf[i] = ldin(ln2w, i, isf32); ln2bf[i] = ldin(ln2b, i, isf32);
            mbf[i]   = ldin(map_b, i, isf32);
            ln3wf[i] = ldin(ln3w, i, isf32); ln3bf[i] = ldin(ln3b, i, isf32);
        }
    } else {
        int cid = (bid - 128) * 256 + threadIdx.x;   // [0, 8192)
        int lane = cid & 63, n4 = (cid >> 6) & 15, br = (cid >> 10) & 1, kb = cid >> 11;
        int o = n4 * 16 + (lane & 15);
        int ch0 = kb * 32 + (lane >> 4) * 8;
        const void* src = br ? map_w : conv_w;
        ushort_t* dst = wfrag + (size_t)cid * 8;
#pragma unroll
        for (int j = 0; j < 8; j++)
            dst[j] = f2bf(ldin(src, o * NC + ch0 + j, isf32));
    }
}

// ---------------------------------------------------------------------------
// K1F v4 = v2 (r10 form, swizzle REVERTED). r11 post-mortem: the oct-XOR
// swizzle cut conflicts only 29% (b128 16B elements have only 8 start-phases;
// the unswizzled pattern is already 8-per-phase = minimum 8-row access) while
// adding per-tap VALU that blocked ds_read offset folding — net SLOWER
// (52.7 -> 54.2). Reverted to the measured-faster linear layout.
// Block 512, grid 1024.
// ---------------------------------------------------------------------------
__global__ __launch_bounds__(512) void k1f(const ushort_t* __restrict__ xT,
                                           const ushort_t* __restrict__ w1b,
                                           const float* __restrict__ b1f,
                                           const ushort_t* __restrict__ w2b,
                                           const float* __restrict__ b2f,
                                           const float* __restrict__ ln1wf,
                                           const float* __restrict__ ln1bf,
                                           ushort_t* __restrict__ y1) {
    __shared__ __align__(16) char smem[52800];   // wkstage, then x8/sred
    __shared__ ushort_t midbuf[64 * 32];
    ushort_t* wkstage = (ushort_t*)smem;
    uint4*    x8      = (uint4*)smem;
    float*    sred    = (float*)smem;

    int t = threadIdx.x;
    int lane = t & 63;
    int w = __builtin_amdgcn_readfirstlane(t >> 6);   // 0..7
    int l16 = lane & 15, quad = lane >> 4;
    int tileid = blockIdx.x;
    int tilex = tileid & 15, tiley = (tileid >> 4) & 15, b = tileid >> 8;
    int h0 = tiley * 8, w0 = tilex * 8;
    int w4 = w & 3;

    // ---- Phase A1: mid = relu(w1 @ x + b1), waves 0..3 (16 px each) ----
    if (w < 4) {
        int lpx = 16 * w + l16;
        int py = lpx >> 3, pxx = lpx & 7;
        const ushort_t* abase = xT + (size_t)((b * NH + h0 + py) * NW + w0 + pxx) * NC + quad * 8;
        floatx4 am0 = (floatx4)0.f, am1 = (floatx4)0.f;
#pragma unroll
        for (int kb = 0; kb < 4; kb++) {
            short8 a   = *(const short8*)(abase + kb * 32);
            short8 b0  = *(const short8*)(w1b + (l16) * NC + kb * 32 + quad * 8);
            short8 b1v = *(const short8*)(w1b + (16 + l16) * NC + kb * 32 + quad * 8);
            am0 = __builtin_amdgcn_mfma_f32_16x16x32_bf16(a, b0, am0, 0, 0, 0);
            am1 = __builtin_amdgcn_mfma_f32_16x16x32_bf16(a, b1v, am1, 0, 0, 0);
        }
        float bia0 = b1f[l16], bia1 = b1f[16 + l16];
#pragma unroll
        for (int r = 0; r < 4; r++) {
            int m = 16 * w + quad * 4 + r;
            midbuf[m * 32 + l16]      = f2bf(fmaxf(am0[r] + bia0, 0.f));
            midbuf[m * 32 + 16 + l16] = f2bf(fmaxf(am1[r] + bia1, 0.f));
        }
    }
    __syncthreads();

    // ---- Phase A2: wk = w2 @ mid + b2 -> wkstage[n][px] (8 waves) ----
    {
        short8 aM = *(const short8*)(midbuf + (16 * w4 + l16) * 32 + quad * 8);
        int nt0 = (w < 4) ? 0 : 13;
        int nt1 = (w < 4) ? 13 : 25;
        for (int nt = nt0; nt < nt1; nt++) {
            int n = nt * 16 + l16;
            short8 bw = *(const short8*)(w2b + n * 32 + quad * 8);
            floatx4 c = __builtin_amdgcn_mfma_f32_16x16x32_bf16(aM, bw, (floatx4)0.f, 0, 0, 0);
            float bias = b2f[n];
#pragma unroll
            for (int r = 0; r < 4; r++)
                wkstage[n * 66 + 16 * w4 + quad * 4 + r] = f2bf(c[r] + bias);
        }
    }
    __syncthreads();

    // ---- wkp preload: lane = px, wave w = group w (conflict-free rows) ----
    uint_t wkp[25];
#pragma unroll
    for (int j = 0; j < 24; j++) {
        uint_t lo = wkstage[(w * NKK + 2 * j) * 66 + lane];
        uint_t hi = wkstage[(w * NKK + 2 * j + 1) * 66 + lane];
        wkp[j] = lo | (hi << 16);
    }
    wkp[24] = wkstage[(w * NKK + 48) * 66 + lane];
    __syncthreads();        // all wk reads complete before LDS reuse

    // ---- Halo staging into x8 (overwrites wkstage; LINEAR layout) ----
    for (int it = 0; it < 7; it++) {
        int idx = it * 512 + t;
        if (idx < 3136) {
            int oct = idx & 15, hp = idx >> 4;
            int hy = hp / 14, hx = hp - hy * 14;
            int gh = h0 + hy - 3, gw = w0 + hx - 3;
            uint4 v = make_uint4(0u, 0u, 0u, 0u);
            if ((unsigned)gh < (unsigned)NH && (unsigned)gw < (unsigned)NW) {
                v = *(const uint4*)&xT[(size_t)((b * NH + gh) * NW + gw) * NC + 8 * oct];
            }
            x8[oct * 197 + hp] = v;
        }
    }
    __syncthreads();

    // ---- Phase B: involution from LDS ----
    int py = lane >> 3, pxx = lane & 7;
    int base0 = py * 14 + pxx;
    float a[16];
#pragma unroll
    for (int j = 0; j < 16; j++) a[j] = 0.f;

#pragma unroll
    for (int tap = 0; tap < NKK; tap++) {
        float wkf = (tap & 1) ? bf2f((ushort_t)(wkp[tap >> 1] >> 16))
                              : bf2f((ushort_t)(wkp[tap >> 1] & 0xffffu));
        int xa = base0 + (tap / 7) * 14 + (tap % 7);
        uint4 u0 = x8[(2 * w) * 197 + xa];
        uint4 u1 = x8[(2 * w + 1) * 197 + xa];
        a[0]  = fmaf(wkf, bf2f_lo(u0.x), a[0]);
        a[1]  = fmaf(wkf, bf2f_hi(u0.x), a[1]);
        a[2]  = fmaf(wkf, bf2f_lo(u0.y), a[2]);
        a[3]  = fmaf(wkf, bf2f_hi(u0.y), a[3]);
        a[4]  = fmaf(wkf, bf2f_lo(u0.z), a[4]);
        a[5]  = fmaf(wkf, bf2f_hi(u0.z), a[5]);
        a[6]  = fmaf(wkf, bf2f_lo(u0.w), a[6]);
        a[7]  = fmaf(wkf, bf2f_hi(u0.w), a[7]);
        a[8]  = fmaf(wkf, bf2f_lo(u1.x), a[8]);
        a[9]  = fmaf(wkf, bf2f_hi(u1.x), a[9]);
        a[10] = fmaf(wkf, bf2f_lo(u1.y), a[10]);
        a[11] = fmaf(wkf, bf2f_hi(u1.y), a[11]);
        a[12] = fmaf(wkf, bf2f_lo(u1.z), a[12]);
        a[13] = fmaf(wkf, bf2f_hi(u1.z), a[13]);
        a[14] = fmaf(wkf, bf2f_lo(u1.w), a[14]);
        a[15] = fmaf(wkf, bf2f_hi(u1.w), a[15]);
    }
    __syncthreads();

    // ---- LN1 over 128 ch (block-wide sred reduction) ----
    float s = 0.f, sq = 0.f;
#pragma unroll
    for (int j = 0; j < 16; j++) { s += a[j]; sq += a[j] * a[j]; }
    sred[(w * 64 + lane) * 2]     = s;
    sred[(w * 64 + lane) * 2 + 1] = sq;
    __syncthreads();
    float ts = 0.f, tq = 0.f;
#pragma unroll
    for (int r = 0; r < 8; r++) {
        ts += sred[(r * 64 + lane) * 2];
        tq += sred[(r * 64 + lane) * 2 + 1];
    }
    float mean = ts * (1.0f / NC);
    float var = tq * (1.0f / NC) - mean * mean;
    float rstd = rsqrtf(var + LN_EPS);

    int p = (b * NH + h0 + py) * NW + w0 + pxx;
    uint_t pk[8];
#pragma unroll
    for (int j = 0; j < 8; j++) {
        int c0 = 16 * w + 2 * j;
        float g0 = gelu_f((a[2 * j] - mean) * rstd * ln1wf[c0] + ln1bf[c0]);
        float g1 = gelu_f((a[2 * j + 1] - mean) * rstd * ln1wf[c0 + 1] + ln1bf[c0 + 1]);
        pk[j] = (uint_t)f2bf(g0) | ((uint_t)f2bf(g1) << 16);
    }
    uint4* dst = (uint4*)(y1 + (size_t)p * NC + 16 * w);
    dst[0] = make_uint4(pk[0], pk[1], pk[2], pk[3]);
    dst[1] = make_uint4(pk[4], pk[5], pk[6], pk[7]);
}

// ---------------------------------------------------------------------------
// K23 v10 (unchanged). o-half split wave pairs; LDS-staged B via
// global_load_lds; streaming epilogue; 64 VGPR + 64 AGPR, no spill.
// grid 2048, block 256.
// ---------------------------------------------------------------------------
__global__ __launch_bounds__(256, 4) void k23(const void* __restrict__ x,
                                              const ushort_t* __restrict__ y1,
                                              const ushort_t* __restrict__ xT,
                                              const ushort_t* __restrict__ wfrag,
                                              const float* __restrict__ mbf,
                                              const float* __restrict__ ln2wf,
                                              const float* __restrict__ ln2bf,
                                              const float* __restrict__ ln3wf,
                                              const float* __restrict__ ln3bf,
                                              void* __restrict__ out) {
    __shared__ __align__(16) char sbuf[32768];   // B stage, reused for stats
    __shared__ int lf;
    int isf32 = sniff_isf32(x, &lf);

    int t = threadIdx.x;
    int lane = t & 63;
    int w = __builtin_amdgcn_readfirstlane(t >> 6);   // 0..3
    int quad = lane >> 4, l16 = lane & 15;
    int pair = w >> 1;                                // 0..1 -> px group
    int oh   = w & 1;                                 // 0..1 -> o-half (128 o's)

    int P0 = blockIdx.x * 32;
    int pw = P0 + pair * 16;                          // this wave's first pixel
    const ushort_t* aYp = y1 + (size_t)(pw + l16) * NC + quad * 8;
    const ushort_t* aXp = xT + (size_t)(pw + l16) * NC + quad * 8;

    // stage kb=0 B-tile (32KB): wave w covers chunks [w*512, w*512+512)
    {
        const ushort_t* gsrc = wfrag + (size_t)(w * 512 + lane) * 8;
        char* ldst = sbuf + (size_t)(w * 512) * 16;
#pragma unroll
        for (int i = 0; i < 8; i++)
            gload_lds16(gsrc + i * 64 * 8, ldst + i * 64 * 16);
    }
    // A operands (both branches) for all 4 k-blocks, hoisted to registers
    short8 Ay[4], Ax[4];
#pragma unroll
    for (int kb = 0; kb < 4; kb++) {
        Ay[kb] = *(const short8*)(aYp + kb * 32);
        Ax[kb] = *(const short8*)(aXp + kb * 32);
    }
    __syncthreads();

    floatx4 accC[8], accM[8];
#pragma unroll
    for (int j = 0; j < 8; j++) { accC[j] = (floatx4)0.f; accM[j] = (floatx4)0.f; }

#pragma unroll
    for (int kb = 0; kb < 4; kb++) {
        short8 ay = Ay[kb], ax = Ax[kb];
#pragma unroll
        for (int j = 0; j < 8; j++) {
            int n4 = oh * 8 + j;
            // tile layout: [br:1][n4:4][lane:6] chunks of 16 B
            short8 bc = *(const short8*)(sbuf + (size_t)(n4 * 64 + lane) * 16);
            short8 bm = *(const short8*)(sbuf + 16384 + (size_t)(n4 * 64 + lane) * 16);
            accC[j] = __builtin_amdgcn_mfma_f32_16x16x32_bf16(ay, bc, accC[j], 0, 0, 0);
            accM[j] = __builtin_amdgcn_mfma_f32_16x16x32_bf16(ax, bm, accM[j], 0, 0, 0);
        }
        __syncthreads();                              // all B reads done
        if (kb < 3) {
            const ushort_t* gsrc = wfrag + ((size_t)(kb + 1) * 2048 + w * 512 + lane) * 8;
            char* ldst = sbuf + (size_t)(w * 512) * 16;
#pragma unroll
            for (int i = 0; i < 8; i++)
                gload_lds16(gsrc + i * 64 * 8, ldst + i * 64 * 16);
            __syncthreads();                          // staging visible (vmcnt drained)
        }
    }

    // map-branch bias (before LN3 stats)
#pragma unroll
    for (int j = 0; j < 8; j++) {
        float mb = mbf[(oh * 8 + j) * 16 + l16];
#pragma unroll
        for (int r = 0; r < 4; r++) accM[j][r] += mb;
    }

    // LN partial stats per px (px = quad*4 + r) over this wave's 128 o's
    floatx4 s1 = (floatx4)0.f, q1 = (floatx4)0.f, s2 = (floatx4)0.f, q2 = (floatx4)0.f;
#pragma unroll
    for (int j = 0; j < 8; j++)
#pragma unroll
        for (int r = 0; r < 4; r++) {
            float a = accC[j][r], m = accM[j][r];
            s1[r] += a; q1[r] += a * a;
            s2[r] += m; q2[r] += m * m;
        }
#pragma unroll
    for (int d = 1; d < 16; d <<= 1) {
#pragma unroll
        for (int r = 0; r < 4; r++) {
            s1[r] += __shfl_xor(s1[r], d);
            q1[r] += __shfl_xor(q1[r], d);
            s2[r] += __shfl_xor(s2[r], d);
            q2[r] += __shfl_xor(q2[r], d);
        }
    }

    // exchange partial stats with the pair's other o-half through sbuf (dead)
    float* sstat = (float*)sbuf;
    if (l16 == 0) {
#pragma unroll
        for (int r = 0; r < 4; r++) {
            float* sp = sstat + (((pair * 2 + oh) * 16) + quad * 4 + r) * 4;
            sp[0] = s1[r]; sp[1] = q1[r]; sp[2] = s2[r]; sp[3] = q2[r];
        }
    }
    __syncthreads();

    floatx4 mn1, rs1, mn2, rs2;
#pragma unroll
    for (int r = 0; r < 4; r++) {
        const float* op = sstat + (((pair * 2 + (oh ^ 1)) * 16) + quad * 4 + r) * 4;
        float S1 = s1[r] + op[0], Q1 = q1[r] + op[1];
        float S2 = s2[r] + op[2], Q2 = q2[r] + op[3];
        mn1[r] = S1 * (1.0f / NO);
        rs1[r] = rsqrtf(Q1 * (1.0f / NO) - mn1[r] * mn1[r] + LN_EPS);
        mn2[r] = S2 * (1.0f / NO);
        rs2[r] = rsqrtf(Q2 * (1.0f / NO) - mn2[r] * mn2[r] + LN_EPS);
    }

    // streaming epilogue: per n4, normalize both branches, gelu, direct store
    int batch = pw >> 14;
    int plocal = (pw & 16383) + quad * 4;
#pragma unroll
    for (int j = 0; j < 8; j++) {
        int o = (oh * 8 + j) * 16 + l16;
        float l2w = ln2wf[o], l2b = ln2bf[o];
        float l3w = ln3wf[o], l3b = ln3bf[o];
        float4 gv;
        {
            float v1, v2;
            v1 = (accC[j][0] - mn1[0]) * rs1[0] * l2w + l2b;
            v2 = (accM[j][0] - mn2[0]) * rs2[0] * l3w + l3b;
            gv.x = gelu_f(v1 + v2);
            v1 = (accC[j][1] - mn1[1]) * rs1[1] * l2w + l2b;
            v2 = (accM[j][1] - mn2[1]) * rs2[1] * l3w + l3b;
            gv.y = gelu_f(v1 + v2);
            v1 = (accC[j][2] - mn1[2]) * rs1[2] * l2w + l2b;
            v2 = (accM[j][2] - mn2[2]) * rs2[2] * l3w + l3b;
            gv.z = gelu_f(v1 + v2);
            v1 = (accC[j][3] - mn1[3]) * rs1[3] * l2w + l2b;
            v2 = (accM[j][3] - mn2[3]) * rs2[3] * l3w + l3b;
            gv.w = gelu_f(v1 + v2);
        }
        size_t oi = ((size_t)(batch * NO + o) << 14) + plocal;
        if (isf32) {
            *(float4*)((float*)out + oi) = gv;
        } else {
            uint_t p0 = (uint_t)f2bf(gv.x) | ((uint_t)f2bf(gv.y) << 16);
            uint_t p1 = (uint_t)f2bf(gv.z) | ((uint_t)f2bf(gv.w) << 16);
            *(uint2*)((ushort_t*)out + oi) = make_uint2(p0, p1);
        }
    }
}

// ---------------------------------------------------------------------------
extern "C" void kernel_launch(void* const* d_in, const int* in_sizes, int n_in,
                              void* d_out, int out_size, void* d_ws, size_t ws_size,
                              hipStream_t stream) {
    const void* x      = d_in[0];
    const void* w1     = d_in[1];
    const void* b1     = d_in[2];
    const void* w2     = d_in[3];
    const void* b2     = d_in[4];
    const void* ln1w   = d_in[5];
    const void* ln1b   = d_in[6];
    const void* conv_w = d_in[7];
    const void* ln2w   = d_in[8];
    const void* ln2b   = d_in[9];
    const void* map_w  = d_in[10];
    const void* map_b  = d_in[11];
    const void* ln3w   = d_in[12];
    const void* ln3b   = d_in[13];

    char* ws = (char*)d_ws;
    ushort_t* xT    = (ushort_t*)(ws);                  // 16,777,216 B
    ushort_t* y1    = (ushort_t*)(ws + 16777216);       // 16,777,216 B
    ushort_t* wfrag = (ushort_t*)(ws + 33554432);       // 131,072 B
    ushort_t* w1b   = (ushort_t*)(ws + 33685504);       //   8,192 B
    ushort_t* w2b   = (ushort_t*)(ws + 33693696);       //  25,600 B
    float*    b1f   = (float*)(ws + 33719296);
    float*    b2f   = (float*)(ws + 33719424);
    float*    ln1wf = (float*)(ws + 33721024);
    float*    ln1bf = (float*)(ws + 33721536);
    float*    mbf   = (float*)(ws + 33722048);
    float*    ln2wf = (float*)(ws + 33723072);
    float*    ln2bf = (float*)(ws + 33724096);
    float*    ln3wf = (float*)(ws + 33725120);
    float*    ln3bf = (float*)(ws + 33726144);
    const size_t NEED_SMALL = 33727184;

    if (ws_size < NEED_SMALL) {
        int nwords = out_size / 2;
        ksentinel<<<(nwords + 255) / 256, 256, 0, stream>>>((uint_t*)d_out, nwords);
        return;
    }

    kprepfrag<<<160, 256, 0, stream>>>(x, w1, w2, b1, b2, ln1w, ln1b,
                                       ln2w, ln2b, map_b, ln3w, ln3b,
                                       conv_w, map_w,
                                       w1b, w2b, b1f, b2f, ln1wf, ln1bf,
                                       ln2wf, ln2bf, mbf, ln3wf, ln3bf, wfrag);
    ktrans<<<dim3(8, 128, 4), 256, 0, stream>>>(x, xT);
    k1f<<<1024, 512, 0, stream>>>(xT, w1b, b1f, w2b, b2f, ln1wf, ln1bf, y1);
    k23<<<NPIX / 32, 256, 0, stream>>>(x, y1, xT, wfrag, mbf,
                                       ln2wf, ln2bf, ln3wf, ln3bf, d_out);
}

// Round 13
// 200.293 us; speedup vs baseline: 1.1158x; 1.0136x over previous
//
#include <hip/hip_runtime.h>

typedef unsigned short ushort_t;
typedef unsigned int uint_t;

#define NB 4
#define NC 128
#define NH 128
#define NW 128
#define NPIX 65536   // NB*NH*NW
#define NMID 32
#define NKK 49
#define NK 392
#define NKP 400      // NK padded to 25 n-tiles of 16
#define NO 256
#define LN_EPS 1e-6f

typedef __attribute__((ext_vector_type(8))) short short8;
typedef __attribute__((ext_vector_type(4))) float floatx4;
typedef __attribute__((ext_vector_type(2))) float floatx2;

__device__ __forceinline__ float bf2f(ushort_t u) {
    union { uint_t i; float f; } v; v.i = ((uint_t)u) << 16; return v.f;
}
__device__ __forceinline__ float bf2f_lo(uint_t u) {
    union { uint_t i; float f; } v; v.i = u << 16; return v.f;
}
__device__ __forceinline__ float bf2f_hi(uint_t u) {
    union { uint_t i; float f; } v; v.i = u & 0xffff0000u; return v.f;
}
// unpack a packed bf16 pair -> floatx2 {lo, hi}
__device__ __forceinline__ floatx2 up2(uint_t u) {
    union { uint_t i; float f; } lo, hi;
    lo.i = u << 16; hi.i = u & 0xffff0000u;
    floatx2 r; r[0] = lo.f; r[1] = hi.f; return r;
}
__device__ __forceinline__ ushort_t f2bf(float f) {
    union { float f; uint_t i; } v; v.f = f;
    uint_t x = v.i;
    uint_t r = (x + 0x7FFFu + ((x >> 16) & 1u)) >> 16;
    return (ushort_t)r;
}
__device__ __forceinline__ float gelu_f(float x) {
    return 0.5f * x * (1.0f + erff(x * 0.70710678118654752f));
}
__device__ __forceinline__ float ldin(const void* p, int i, int isf32) {
    return isf32 ? ((const float*)p)[i] : bf2f(((const ushort_t*)p)[i]);
}
// global -> LDS direct DMA, 16B per lane; LDS dest = uniform base + lane*16
__device__ __forceinline__ void gload_lds16(const void* g, void* l) {
    __builtin_amdgcn_global_load_lds(
        (const __attribute__((address_space(1))) void*)g,
        (__attribute__((address_space(3))) void*)l, 16, 0, 0);
}

// ---------------------------------------------------------------------------
// Per-block dtype sniff (in_sizes are ELEMENT counts — r8 post-mortem — so
// runtime sniffing is required). One wave computes, broadcast via LDS.
// ---------------------------------------------------------------------------
__device__ __forceinline__ int sniff_isf32(const void* x, int* lf) {
    int t = threadIdx.x;
    if (t < 64) {
        const uint_t* xw = (const uint_t*)x;
        int cnt = 0;
#pragma unroll
        for (int j = 0; j < 8; j++) {
            uint_t wv = xw[t * 8 + j];
            uint_t e = (wv >> 7) & 0xffu;
            if (e >= 110u && e <= 135u) cnt++;
        }
#pragma unroll
        for (int d = 1; d < 64; d <<= 1) cnt += __shfl_xor(cnt, d);
        if (t == 0) *lf = (cnt < 256) ? 1 : 0;
    }
    __syncthreads();
    return *lf;
}

__global__ void ksentinel(uint_t* __restrict__ out, int nwords) {
    int i = blockIdx.x * 256 + threadIdx.x;
    if (i < nwords) out[i] = 0x40004000u;
}

// ---------------------------------------------------------------------------
// KPF: merged transpose + param-prep + fragment repack (was 2 dispatches;
// r12 accounting shows ~85us of launch/serialization overhead -> cut a gap).
// Blocks [0,4096): ktrans v3 body (b=bid>>10, h=(bid>>3)&127, chunk=bid&7).
// Blocks [4096,4224): param prep. Blocks [4224,4256): conv/map frag repack
// (cid = [kb:2][br:1][n4:4][lane:6] chunks of 8 bf16; kb-tiles contiguous
// -> linear global_load_lds target in k23). grid 4256, block 256.
// ---------------------------------------------------------------------------
__global__ __launch_bounds__(256) void kpf(const void* x,
                                           const void* w1, const void* w2,
                                           const void* b1, const void* b2,
                                           const void* ln1w, const void* ln1b,
                                           const void* ln2w, const void* ln2b,
                                           const void* map_b,
                                           const void* ln3w, const void* ln3b,
                                           const void* conv_w, const void* map_w,
                                           ushort_t* __restrict__ xT,
                                           ushort_t* __restrict__ w1b,
                                           ushort_t* __restrict__ w2b,
                                           float* __restrict__ b1f,
                                           float* __restrict__ b2f,
                                           float* __restrict__ ln1wf,
                                           float* __restrict__ ln1bf,
                                           float* __restrict__ ln2wf,
                                           float* __restrict__ ln2bf,
                                           float* __restrict__ mbf,
                                           float* __restrict__ ln3wf,
                                           float* __restrict__ ln3bf,
                                           ushort_t* __restrict__ wfrag) {
    __shared__ __align__(16) ushort_t tile[32][72];
    __shared__ int lf;
    int isf32 = sniff_isf32(x, &lf);
    int bid = blockIdx.x;
    int t = threadIdx.x;

    if (bid < 4096) {
        int b = bid >> 10, h = (bid >> 3) & 127;
        int wchunk = bid & 1, cchunk = (bid >> 1) & 3;
        int w0 = wchunk << 6, c0 = cchunk << 5;
        {
            int cc = t >> 3, wseg = t & 7;
            size_t idx = (size_t)((b * NC + c0 + cc) * NH + h) * NW + w0 + wseg * 8;
            uint4 pk;
            if (isf32) {
                float4 f0 = *(const float4*)((const float*)x + idx);
                float4 f1 = *(const float4*)((const float*)x + idx + 4);
                pk.x = (uint_t)f2bf(f0.x) | ((uint_t)f2bf(f0.y) << 16);
                pk.y = (uint_t)f2bf(f0.z) | ((uint_t)f2bf(f0.w) << 16);
                pk.z = (uint_t)f2bf(f1.x) | ((uint_t)f2bf(f1.y) << 16);
                pk.w = (uint_t)f2bf(f1.z) | ((uint_t)f2bf(f1.w) << 16);
            } else {
                pk = *(const uint4*)((const ushort_t*)x + idx);
            }
            *(uint4*)&tile[cc][wseg * 8] = pk;
        }
        __syncthreads();
        int px = t >> 2, seg = t & 3;
        ushort_t o[8];
#pragma unroll
        for (int j = 0; j < 8; j++) o[j] = tile[seg * 8 + j][px];
        *(uint4*)&xT[((size_t)((b * NH + h) * NW) + w0 + px) * NC + c0 + seg * 8]
            = *(uint4*)o;
    } else if (bid < 4224) {
        int i = (bid - 4096) * 256 + t;
        if (i < NMID * NC) w1b[i] = f2bf(ldin(w1, i, isf32));
        if (i < NKP * NMID) w2b[i] = (i < NK * NMID) ? f2bf(ldin(w2, i, isf32))
                                                     : (ushort_t)0;
        if (i < NMID) b1f[i] = ldin(b1, i, isf32);
        if (i < NKP)  b2f[i] = (i < NK) ? ldin(b2, i, isf32) : 0.f;
        if (i < NC) { ln1wf[i] = ldin(ln1w, i, isf32); ln1bf[i] = ldin(ln1b, i, isf32); }
        if (i < NO) {
            ln2wf[i] = ldin(ln2w, i, isf32); ln2bf[i] = ldin(ln2b, i, isf32);
            mbf[i]   = ldin(map_b, i, isf32);
            ln3wf[i] = ldin(ln3w, i, isf32); ln3bf[i] = ldin(ln3b, i, isf32);
        }
    } else {
        int cid = (bid - 4224) * 256 + t;   // [0, 8192)
        int lane = cid & 63, n4 = (cid >> 6) & 15, br = (cid >> 10) & 1, kb = cid >> 11;
        int o = n4 * 16 + (lane & 15);
        int ch0 = kb * 32 + (lane >> 4) * 8;
        const void* src = br ? map_w : conv_w;
        ushort_t* dst = wfrag + (size_t)cid * 8;
#pragma unroll
        for (int j = 0; j < 8; j++)
            dst[j] = f2bf(ldin(src, o * NC + ch0 + j, isf32));
    }
}

// ---------------------------------------------------------------------------
// K1F v5 = v4 with phase-B accumulators as floatx2 (v2f32 fma -> the backend
// can select v_pk_fma_f32: one instruction per 2 channels, halving the 784
// scalar v_fmac issues that dominate the 64%-VALUBusy loop). Per-channel fma
// order and rounding identical -> bit-identical results. Linear x8 layout
// (r11 showed the 6.93M "conflicts" are irreducible b128 bandwidth).
// Block 512, grid 1024.
// ---------------------------------------------------------------------------
__global__ __launch_bounds__(512) void k1f(const ushort_t* __restrict__ xT,
                                           const ushort_t* __restrict__ w1b,
                                           const float* __restrict__ b1f,
                                           const ushort_t* __restrict__ w2b,
                                           const float* __restrict__ b2f,
                                           const float* __restrict__ ln1wf,
                                           const float* __restrict__ ln1bf,
                                           ushort_t* __restrict__ y1) {
    __shared__ __align__(16) char smem[52800];   // wkstage, then x8/sred
    __shared__ ushort_t midbuf[64 * 32];
    ushort_t* wkstage = (ushort_t*)smem;
    uint4*    x8      = (uint4*)smem;
    float*    sred    = (float*)smem;

    int t = threadIdx.x;
    int lane = t & 63;
    int w = __builtin_amdgcn_readfirstlane(t >> 6);   // 0..7
    int l16 = lane & 15, quad = lane >> 4;
    int tileid = blockIdx.x;
    int tilex = tileid & 15, tiley = (tileid >> 4) & 15, b = tileid >> 8;
    int h0 = tiley * 8, w0 = tilex * 8;
    int w4 = w & 3;

    // ---- Phase A1: mid = relu(w1 @ x + b1), waves 0..3 (16 px each) ----
    if (w < 4) {
        int lpx = 16 * w + l16;
        int py = lpx >> 3, pxx = lpx & 7;
        const ushort_t* abase = xT + (size_t)((b * NH + h0 + py) * NW + w0 + pxx) * NC + quad * 8;
        floatx4 am0 = (floatx4)0.f, am1 = (floatx4)0.f;
#pragma unroll
        for (int kb = 0; kb < 4; kb++) {
            short8 a   = *(const short8*)(abase + kb * 32);
            short8 b0  = *(const short8*)(w1b + (l16) * NC + kb * 32 + quad * 8);
            short8 b1v = *(const short8*)(w1b + (16 + l16) * NC + kb * 32 + quad * 8);
            am0 = __builtin_amdgcn_mfma_f32_16x16x32_bf16(a, b0, am0, 0, 0, 0);
            am1 = __builtin_amdgcn_mfma_f32_16x16x32_bf16(a, b1v, am1, 0, 0, 0);
        }
        float bia0 = b1f[l16], bia1 = b1f[16 + l16];
#pragma unroll
        for (int r = 0; r < 4; r++) {
            int m = 16 * w + quad * 4 + r;
            midbuf[m * 32 + l16]      = f2bf(fmaxf(am0[r] + bia0, 0.f));
            midbuf[m * 32 + 16 + l16] = f2bf(fmaxf(am1[r] + bia1, 0.f));
        }
    }
    __syncthreads();

    // ---- Phase A2: wk = w2 @ mid + b2 -> wkstage[n][px] (8 waves) ----
    {
        short8 aM = *(const short8*)(midbuf + (16 * w4 + l16) * 32 + quad * 8);
        int nt0 = (w < 4) ? 0 : 13;
        int nt1 = (w < 4) ? 13 : 25;
        for (int nt = nt0; nt < nt1; nt++) {
            int n = nt * 16 + l16;
            short8 bw = *(const short8*)(w2b + n * 32 + quad * 8);
            floatx4 c = __builtin_amdgcn_mfma_f32_16x16x32_bf16(aM, bw, (floatx4)0.f, 0, 0, 0);
            float bias = b2f[n];
#pragma unroll
            for (int r = 0; r < 4; r++)
                wkstage[n * 66 + 16 * w4 + quad * 4 + r] = f2bf(c[r] + bias);
        }
    }
    __syncthreads();

    // ---- wkp preload: lane = px, wave w = group w (conflict-free rows) ----
    uint_t wkp[25];
#pragma unroll
    for (int j = 0; j < 24; j++) {
        uint_t lo = wkstage[(w * NKK + 2 * j) * 66 + lane];
        uint_t hi = wkstage[(w * NKK + 2 * j + 1) * 66 + lane];
        wkp[j] = lo | (hi << 16);
    }
    wkp[24] = wkstage[(w * NKK + 48) * 66 + lane];
    __syncthreads();        // all wk reads complete before LDS reuse

    // ---- Halo staging into x8 (overwrites wkstage; LINEAR layout) ----
    for (int it = 0; it < 7; it++) {
        int idx = it * 512 + t;
        if (idx < 3136) {
            int oct = idx & 15, hp = idx >> 4;
            int hy = hp / 14, hx = hp - hy * 14;
            int gh = h0 + hy - 3, gw = w0 + hx - 3;
            uint4 v = make_uint4(0u, 0u, 0u, 0u);
            if ((unsigned)gh < (unsigned)NH && (unsigned)gw < (unsigned)NW) {
                v = *(const uint4*)&xT[(size_t)((b * NH + gh) * NW + gw) * NC + 8 * oct];
            }
            x8[oct * 197 + hp] = v;
        }
    }
    __syncthreads();

    // ---- Phase B: involution from LDS, packed v2f32 accumulate ----
    int py = lane >> 3, pxx = lane & 7;
    int base0 = py * 14 + pxx;
    floatx2 a2[8];
#pragma unroll
    for (int j = 0; j < 8; j++) a2[j] = (floatx2)0.f;

#pragma unroll
    for (int tap = 0; tap < NKK; tap++) {
        float wkf = (tap & 1) ? bf2f((ushort_t)(wkp[tap >> 1] >> 16))
                              : bf2f((ushort_t)(wkp[tap >> 1] & 0xffffu));
        floatx2 wk2 = (floatx2)wkf;
        int xa = base0 + (tap / 7) * 14 + (tap % 7);
        uint4 u0 = x8[(2 * w) * 197 + xa];
        uint4 u1 = x8[(2 * w + 1) * 197 + xa];
        a2[0] = wk2 * up2(u0.x) + a2[0];
        a2[1] = wk2 * up2(u0.y) + a2[1];
        a2[2] = wk2 * up2(u0.z) + a2[2];
        a2[3] = wk2 * up2(u0.w) + a2[3];
        a2[4] = wk2 * up2(u1.x) + a2[4];
        a2[5] = wk2 * up2(u1.y) + a2[5];
        a2[6] = wk2 * up2(u1.z) + a2[6];
        a2[7] = wk2 * up2(u1.w) + a2[7];
    }
    __syncthreads();

    // ---- LN1 over 128 ch (block-wide sred reduction; same accum order) ----
    float s = 0.f, sq = 0.f;
#pragma unroll
    for (int j = 0; j < 8; j++) {
        float v0 = a2[j][0], v1 = a2[j][1];
        s += v0; sq += v0 * v0;
        s += v1; sq += v1 * v1;
    }
    sred[(w * 64 + lane) * 2]     = s;
    sred[(w * 64 + lane) * 2 + 1] = sq;
    __syncthreads();
    float ts = 0.f, tq = 0.f;
#pragma unroll
    for (int r = 0; r < 8; r++) {
        ts += sred[(r * 64 + lane) * 2];
        tq += sred[(r * 64 + lane) * 2 + 1];
    }
    float mean = ts * (1.0f / NC);
    float var = tq * (1.0f / NC) - mean * mean;
    float rstd = rsqrtf(var + LN_EPS);

    int p = (b * NH + h0 + py) * NW + w0 + pxx;
    uint_t pk[8];
#pragma unroll
    for (int j = 0; j < 8; j++) {
        int c0 = 16 * w + 2 * j;
        float g0 = gelu_f((a2[j][0] - mean) * rstd * ln1wf[c0] + ln1bf[c0]);
        float g1 = gelu_f((a2[j][1] - mean) * rstd * ln1wf[c0 + 1] + ln1bf[c0 + 1]);
        pk[j] = (uint_t)f2bf(g0) | ((uint_t)f2bf(g1) << 16);
    }
    uint4* dst = (uint4*)(y1 + (size_t)p * NC + 16 * w);
    dst[0] = make_uint4(pk[0], pk[1], pk[2], pk[3]);
    dst[1] = make_uint4(pk[4], pk[5], pk[6], pk[7]);
}

// ---------------------------------------------------------------------------
// K23 v10 (unchanged). o-half split wave pairs; LDS-staged B via
// global_load_lds; streaming epilogue; 64 VGPR + 64 AGPR, no spill.
// grid 2048, block 256.
// ---------------------------------------------------------------------------
__global__ __launch_bounds__(256, 4) void k23(const void* __restrict__ x,
                                              const ushort_t* __restrict__ y1,
                                              const ushort_t* __restrict__ xT,
                                              const ushort_t* __restrict__ wfrag,
                                              const float* __restrict__ mbf,
                                              const float* __restrict__ ln2wf,
                                              const float* __restrict__ ln2bf,
                                              const float* __restrict__ ln3wf,
                                              const float* __restrict__ ln3bf,
                                              void* __restrict__ out) {
    __shared__ __align__(16) char sbuf[32768];   // B stage, reused for stats
    __shared__ int lf;
    int isf32 = sniff_isf32(x, &lf);

    int t = threadIdx.x;
    int lane = t & 63;
    int w = __builtin_amdgcn_readfirstlane(t >> 6);   // 0..3
    int quad = lane >> 4, l16 = lane & 15;
    int pair = w >> 1;                                // 0..1 -> px group
    int oh   = w & 1;                                 // 0..1 -> o-half (128 o's)

    int P0 = blockIdx.x * 32;
    int pw = P0 + pair * 16;                          // this wave's first pixel
    const ushort_t* aYp = y1 + (size_t)(pw + l16) * NC + quad * 8;
    const ushort_t* aXp = xT + (size_t)(pw + l16) * NC + quad * 8;

    // stage kb=0 B-tile (32KB): wave w covers chunks [w*512, w*512+512)
    {
        const ushort_t* gsrc = wfrag + (size_t)(w * 512 + lane) * 8;
        char* ldst = sbuf + (size_t)(w * 512) * 16;
#pragma unroll
        for (int i = 0; i < 8; i++)
            gload_lds16(gsrc + i * 64 * 8, ldst + i * 64 * 16);
    }
    // A operands (both branches) for all 4 k-blocks, hoisted to registers
    short8 Ay[4], Ax[4];
#pragma unroll
    for (int kb = 0; kb < 4; kb++) {
        Ay[kb] = *(const short8*)(aYp + kb * 32);
        Ax[kb] = *(const short8*)(aXp + kb * 32);
    }
    __syncthreads();

    floatx4 accC[8], accM[8];
#pragma unroll
    for (int j = 0; j < 8; j++) { accC[j] = (floatx4)0.f; accM[j] = (floatx4)0.f; }

#pragma unroll
    for (int kb = 0; kb < 4; kb++) {
        short8 ay = Ay[kb], ax = Ax[kb];
#pragma unroll
        for (int j = 0; j < 8; j++) {
            int n4 = oh * 8 + j;
            // tile layout: [br:1][n4:4][lane:6] chunks of 16 B
            short8 bc = *(const short8*)(sbuf + (size_t)(n4 * 64 + lane) * 16);
            short8 bm = *(const short8*)(sbuf + 16384 + (size_t)(n4 * 64 + lane) * 16);
            accC[j] = __builtin_amdgcn_mfma_f32_16x16x32_bf16(ay, bc, accC[j], 0, 0, 0);
            accM[j] = __builtin_amdgcn_mfma_f32_16x16x32_bf16(ax, bm, accM[j], 0, 0, 0);
        }
        __syncthreads();                              // all B reads done
        if (kb < 3) {
            const ushort_t* gsrc = wfrag + ((size_t)(kb + 1) * 2048 + w * 512 + lane) * 8;
            char* ldst = sbuf + (size_t)(w * 512) * 16;
#pragma unroll
            for (int i = 0; i < 8; i++)
                gload_lds16(gsrc + i * 64 * 8, ldst + i * 64 * 16);
            __syncthreads();                          // staging visible (vmcnt drained)
        }
    }

    // map-branch bias (before LN3 stats)
#pragma unroll
    for (int j = 0; j < 8; j++) {
        float mb = mbf[(oh * 8 + j) * 16 + l16];
#pragma unroll
        for (int r = 0; r < 4; r++) accM[j][r] += mb;
    }

    // LN partial stats per px (px = quad*4 + r) over this wave's 128 o's
    floatx4 s1 = (floatx4)0.f, q1 = (floatx4)0.f, s2 = (floatx4)0.f, q2 = (floatx4)0.f;
#pragma unroll
    for (int j = 0; j < 8; j++)
#pragma unroll
        for (int r = 0; r < 4; r++) {
            float a = accC[j][r], m = accM[j][r];
            s1[r] += a; q1[r] += a * a;
            s2[r] += m; q2[r] += m * m;
        }
#pragma unroll
    for (int d = 1; d < 16; d <<= 1) {
#pragma unroll
        for (int r = 0; r < 4; r++) {
            s1[r] += __shfl_xor(s1[r], d);
            q1[r] += __shfl_xor(q1[r], d);
            s2[r] += __shfl_xor(s2[r], d);
            q2[r] += __shfl_xor(q2[r], d);
        }
    }

    // exchange partial stats with the pair's other o-half through sbuf (dead)
    float* sstat = (float*)sbuf;
    if (l16 == 0) {
#pragma unroll
        for (int r = 0; r < 4; r++) {
            float* sp = sstat + (((pair * 2 + oh) * 16) + quad * 4 + r) * 4;
            sp[0] = s1[r]; sp[1] = q1[r]; sp[2] = s2[r]; sp[3] = q2[r];
        }
    }
    __syncthreads();

    floatx4 mn1, rs1, mn2, rs2;
#pragma unroll
    for (int r = 0; r < 4; r++) {
        const float* op = sstat + (((pair * 2 + (oh ^ 1)) * 16) + quad * 4 + r) * 4;
        float S1 = s1[r] + op[0], Q1 = q1[r] + op[1];
        float S2 = s2[r] + op[2], Q2 = q2[r] + op[3];
        mn1[r] = S1 * (1.0f / NO);
        rs1[r] = rsqrtf(Q1 * (1.0f / NO) - mn1[r] * mn1[r] + LN_EPS);
        mn2[r] = S2 * (1.0f / NO);
        rs2[r] = rsqrtf(Q2 * (1.0f / NO) - mn2[r] * mn2[r] + LN_EPS);
    }

    // streaming epilogue: per n4, normalize both branches, gelu, direct store
    int batch = pw >> 14;
    int plocal = (pw & 16383) + quad * 4;
#pragma unroll
    for (int j = 0; j < 8; j++) {
        int o = (oh * 8 + j) * 16 + l16;
        float l2w = ln2wf[o], l2b = ln2bf[o];
        float l3w = ln3wf[o], l3b = ln3bf[o];
        float4 gv;
        {
            float v1, v2;
            v1 = (accC[j][0] - mn1[0]) * rs1[0] * l2w + l2b;
            v2 = (accM[j][0] - mn2[0]) * rs2[0] * l3w + l3b;
            gv.x = gelu_f(v1 + v2);
            v1 = (accC[j][1] - mn1[1]) * rs1[1] * l2w + l2b;
            v2 = (accM[j][1] - mn2[1]) * rs2[1] * l3w + l3b;
            gv.y = gelu_f(v1 + v2);
            v1 = (accC[j][2] - mn1[2]) * rs1[2] * l2w + l2b;
            v2 = (accM[j][2] - mn2[2]) * rs2[2] * l3w + l3b;
            gv.z = gelu_f(v1 + v2);
            v1 = (accC[j][3] - mn1[3]) * rs1[3] * l2w + l2b;
            v2 = (accM[j][3] - mn2[3]) * rs2[3] * l3w + l3b;
            gv.w = gelu_f(v1 + v2);
        }
        size_t oi = ((size_t)(batch * NO + o) << 14) + plocal;
        if (isf32) {
            *(float4*)((float*)out + oi) = gv;
        } else {
            uint_t p0 = (uint_t)f2bf(gv.x) | ((uint_t)f2bf(gv.y) << 16);
            uint_t p1 = (uint_t)f2bf(gv.z) | ((uint_t)f2bf(gv.w) << 16);
            *(uint2*)((ushort_t*)out + oi) = make_uint2(p0, p1);
        }
    }
}

// ---------------------------------------------------------------------------
extern "C" void kernel_launch(void* const* d_in, const int* in_sizes, int n_in,
                              void* d_out, int out_size, void* d_ws, size_t ws_size,
                              hipStream_t stream) {
    const void* x      = d_in[0];
    const void* w1     = d_in[1];
    const void* b1     = d_in[2];
    const void* w2     = d_in[3];
    const void* b2     = d_in[4];
    const void* ln1w   = d_in[5];
    const void* ln1b   = d_in[6];
    const void* conv_w = d_in[7];
    const void* ln2w   = d_in[8];
    const void* ln2b   = d_in[9];
    const void* map_w  = d_in[10];
    const void* map_b  = d_in[11];
    const void* ln3w   = d_in[12];
    const void* ln3b   = d_in[13];

    char* ws = (char*)d_ws;
    ushort_t* xT    = (ushort_t*)(ws);                  // 16,777,216 B
    ushort_t* y1    = (ushort_t*)(ws + 16777216);       // 16,777,216 B
    ushort_t* wfrag = (ushort_t*)(ws + 33554432);       // 131,072 B
    ushort_t* w1b   = (ushort_t*)(ws + 33685504);       //   8,192 B
    ushort_t* w2b   = (ushort_t*)(ws + 33693696);       //  25,600 B
    float*    b1f   = (float*)(ws + 33719296);
    float*    b2f   = (float*)(ws + 33719424);
    float*    ln1wf = (float*)(ws + 33721024);
    float*    ln1bf = (float*)(ws + 33721536);
    float*    mbf   = (float*)(ws + 33722048);
    float*    ln2wf = (float*)(ws + 33723072);
    float*    ln2bf = (float*)(ws + 33724096);
    float*    ln3wf = (float*)(ws + 33725120);
    float*    ln3bf = (float*)(ws + 33726144);
    const size_t NEED_SMALL = 33727184;

    if (ws_size < NEED_SMALL) {
        int nwords = out_size / 2;
        ksentinel<<<(nwords + 255) / 256, 256, 0, stream>>>((uint_t*)d_out, nwords);
        return;
    }

    kpf<<<4256, 256, 0, stream>>>(x, w1, w2, b1, b2, ln1w, ln1b,
                                  ln2w, ln2b, map_b, ln3w, ln3b,
                                  conv_w, map_w, xT,
                                  w1b, w2b, b1f, b2f, ln1wf, ln1bf,
                                  ln2wf, ln2bf, mbf, ln3wf, ln3bf, wfrag);
    k1f<<<1024, 512, 0, stream>>>(xT, w1b, b1f, w2b, b2f, ln1wf, ln1bf, y1);
    k23<<<NPIX / 32, 256, 0, stream>>>(x, y1, xT, wfrag, mbf,
                                       ln2wf, ln2bf, ln3wf, ln3bf, d_out);
}

// Round 14
// 196.743 us; speedup vs baseline: 1.1359x; 1.0180x over previous
//
#include <hip/hip_runtime.h>

typedef unsigned short ushort_t;
typedef unsigned int uint_t;

#define NB 4
#define NC 128
#define NH 128
#define NW 128
#define NPIX 65536   // NB*NH*NW
#define NMID 32
#define NKK 49
#define NK 392
#define NKP 400      // NK padded to 25 n-tiles of 16
#define NO 256
#define LN_EPS 1e-6f

typedef __attribute__((ext_vector_type(8))) short short8;
typedef __attribute__((ext_vector_type(4))) float floatx4;
typedef __attribute__((ext_vector_type(2))) float floatx2;

__device__ __forceinline__ float bf2f(ushort_t u) {
    union { uint_t i; float f; } v; v.i = ((uint_t)u) << 16; return v.f;
}
__device__ __forceinline__ float bf2f_lo(uint_t u) {
    union { uint_t i; float f; } v; v.i = u << 16; return v.f;
}
__device__ __forceinline__ float bf2f_hi(uint_t u) {
    union { uint_t i; float f; } v; v.i = u & 0xffff0000u; return v.f;
}
// unpack a packed bf16 pair -> floatx2 {lo, hi}
__device__ __forceinline__ floatx2 up2(uint_t u) {
    union { uint_t i; float f; } lo, hi;
    lo.i = u << 16; hi.i = u & 0xffff0000u;
    floatx2 r; r[0] = lo.f; r[1] = hi.f; return r;
}
__device__ __forceinline__ ushort_t f2bf(float f) {
    union { float f; uint_t i; } v; v.f = f;
    uint_t x = v.i;
    uint_t r = (x + 0x7FFFu + ((x >> 16) & 1u)) >> 16;
    return (ushort_t)r;
}
__device__ __forceinline__ float gelu_f(float x) {
    return 0.5f * x * (1.0f + erff(x * 0.70710678118654752f));
}
__device__ __forceinline__ float ldin(const void* p, int i, int isf32) {
    return isf32 ? ((const float*)p)[i] : bf2f(((const ushort_t*)p)[i]);
}
// global -> LDS direct DMA, 16B per lane; LDS dest = uniform base + lane*16
__device__ __forceinline__ void gload_lds16(const void* g, void* l) {
    __builtin_amdgcn_global_load_lds(
        (const __attribute__((address_space(1))) void*)g,
        (__attribute__((address_space(3))) void*)l, 16, 0, 0);
}

// ---------------------------------------------------------------------------
// Per-block dtype sniff (in_sizes are ELEMENT counts — r8 post-mortem — so
// runtime sniffing is required). One wave computes, broadcast via LDS.
// ---------------------------------------------------------------------------
__device__ __forceinline__ int sniff_isf32(const void* x, int* lf) {
    int t = threadIdx.x;
    if (t < 64) {
        const uint_t* xw = (const uint_t*)x;
        int cnt = 0;
#pragma unroll
        for (int j = 0; j < 8; j++) {
            uint_t wv = xw[t * 8 + j];
            uint_t e = (wv >> 7) & 0xffu;
            if (e >= 110u && e <= 135u) cnt++;
        }
#pragma unroll
        for (int d = 1; d < 64; d <<= 1) cnt += __shfl_xor(cnt, d);
        if (t == 0) *lf = (cnt < 256) ? 1 : 0;
    }
    __syncthreads();
    return *lf;
}

__global__ void ksentinel(uint_t* __restrict__ out, int nwords) {
    int i = blockIdx.x * 256 + threadIdx.x;
    if (i < nwords) out[i] = 0x40004000u;
}

// ---------------------------------------------------------------------------
// KPF: merged transpose + param-prep + fragment repack (3-dispatch pipeline).
// Blocks [0,4096): ktrans v3 body. Blocks [4096,4224): param prep.
// Blocks [4224,4256): conv/map frag repack (cid = [kb:2][br:1][n4:4][lane:6]
// chunks of 8 bf16; kb-tiles contiguous -> linear global_load_lds in k23).
// grid 4256, block 256.
// ---------------------------------------------------------------------------
__global__ __launch_bounds__(256) void kpf(const void* x,
                                           const void* w1, const void* w2,
                                           const void* b1, const void* b2,
                                           const void* ln1w, const void* ln1b,
                                           const void* ln2w, const void* ln2b,
                                           const void* map_b,
                                           const void* ln3w, const void* ln3b,
                                           const void* conv_w, const void* map_w,
                                           ushort_t* __restrict__ xT,
                                           ushort_t* __restrict__ w1b,
                                           ushort_t* __restrict__ w2b,
                                           float* __restrict__ b1f,
                                           float* __restrict__ b2f,
                                           float* __restrict__ ln1wf,
                                           float* __restrict__ ln1bf,
                                           float* __restrict__ ln2wf,
                                           float* __restrict__ ln2bf,
                                           float* __restrict__ mbf,
                                           float* __restrict__ ln3wf,
                                           float* __restrict__ ln3bf,
                                           ushort_t* __restrict__ wfrag) {
    __shared__ __align__(16) ushort_t tile[32][72];
    __shared__ int lf;
    int isf32 = sniff_isf32(x, &lf);
    int bid = blockIdx.x;
    int t = threadIdx.x;

    if (bid < 4096) {
        int b = bid >> 10, h = (bid >> 3) & 127;
        int wchunk = bid & 1, cchunk = (bid >> 1) & 3;
        int w0 = wchunk << 6, c0 = cchunk << 5;
        {
            int cc = t >> 3, wseg = t & 7;
            size_t idx = (size_t)((b * NC + c0 + cc) * NH + h) * NW + w0 + wseg * 8;
            uint4 pk;
            if (isf32) {
                float4 f0 = *(const float4*)((const float*)x + idx);
                float4 f1 = *(const float4*)((const float*)x + idx + 4);
                pk.x = (uint_t)f2bf(f0.x) | ((uint_t)f2bf(f0.y) << 16);
                pk.y = (uint_t)f2bf(f0.z) | ((uint_t)f2bf(f0.w) << 16);
                pk.z = (uint_t)f2bf(f1.x) | ((uint_t)f2bf(f1.y) << 16);
                pk.w = (uint_t)f2bf(f1.z) | ((uint_t)f2bf(f1.w) << 16);
            } else {
                pk = *(const uint4*)((const ushort_t*)x + idx);
            }
            *(uint4*)&tile[cc][wseg * 8] = pk;
        }
        __syncthreads();
        int px = t >> 2, seg = t & 3;
        ushort_t o[8];
#pragma unroll
        for (int j = 0; j < 8; j++) o[j] = tile[seg * 8 + j][px];
        *(uint4*)&xT[((size_t)((b * NH + h) * NW) + w0 + px) * NC + c0 + seg * 8]
            = *(uint4*)o;
    } else if (bid < 4224) {
        int i = (bid - 4096) * 256 + t;
        if (i < NMID * NC) w1b[i] = f2bf(ldin(w1, i, isf32));
        if (i < NKP * NMID) w2b[i] = (i < NK * NMID) ? f2bf(ldin(w2, i, isf32))
                                                     : (ushort_t)0;
        if (i < NMID) b1f[i] = ldin(b1, i, isf32);
        if (i < NKP)  b2f[i] = (i < NK) ? ldin(b2, i, isf32) : 0.f;
        if (i < NC) { ln1wf[i] = ldin(ln1w, i, isf32); ln1bf[i] = ldin(ln1b, i, isf32); }
        if (i < NO) {
            ln2wf[i] = ldin(ln2w, i, isf32); ln2bf[i] = ldin(ln2b, i, isf32);
            mbf[i]   = ldin(map_b, i, isf32);
            ln3wf[i] = ldin(ln3w, i, isf32); ln3bf[i] = ldin(ln3b, i, isf32);
        }
    } else {
        int cid = (bid - 4224) * 256 + t;   // [0, 8192)
        int lane = cid & 63, n4 = (cid >> 6) & 15, br = (cid >> 10) & 1, kb = cid >> 11;
        int o = n4 * 16 + (lane & 15);
        int ch0 = kb * 32 + (lane >> 4) * 8;
        const void* src = br ? map_w : conv_w;
        ushort_t* dst = wfrag + (size_t)cid * 8;
#pragma unroll
        for (int j = 0; j < 8; j++)
            dst[j] = f2bf(ldin(src, o * NC + ch0 + j, isf32));
    }
}

// ---------------------------------------------------------------------------
// K1F v6: phase B remapped to 2-ADJACENT-PX PER LANE, 8 ch per lane
// (t -> oct gg=t>>5, pair pp=t&31; px0=py*8+2ppx, px1=px0+1). Adjacent px
// share 6/7 of their tap windows: per halo row the pair's union is 8
// positions -> ONE b128 read + 8 unpacks feed BOTH pixels' pk_fmas.
// LDS b128 reads/block 50176 -> 28672 (1.75x), unpacks ~halved, fma count
// unchanged. wk preload: one u32 packs both px for tap k; wave-uniform row
// -> broadcast, conflict-free; 49 regs. LN: shfl_xor(32) + 8-wave LDS
// reduce (stride-5 pad, conflict-free). Same per-px tap order -> same
// per-channel sums. Block 512, grid 1024.
// ---------------------------------------------------------------------------
__global__ __launch_bounds__(512) void k1f(const ushort_t* __restrict__ xT,
                                           const ushort_t* __restrict__ w1b,
                                           const float* __restrict__ b1f,
                                           const ushort_t* __restrict__ w2b,
                                           const float* __restrict__ b2f,
                                           const float* __restrict__ ln1wf,
                                           const float* __restrict__ ln1bf,
                                           ushort_t* __restrict__ y1) {
    __shared__ __align__(16) char smem[52800];   // wkstage, then x8/sred
    __shared__ ushort_t midbuf[64 * 32];
    ushort_t* wkstage = (ushort_t*)smem;
    uint4*    x8      = (uint4*)smem;

    int t = threadIdx.x;
    int lane = t & 63;
    int w = __builtin_amdgcn_readfirstlane(t >> 6);   // 0..7
    int l16 = lane & 15, quad = lane >> 4;
    int tileid = blockIdx.x;
    int tilex = tileid & 15, tiley = (tileid >> 4) & 15, b = tileid >> 8;
    int h0 = tiley * 8, w0 = tilex * 8;
    int w4 = w & 3;

    // ---- Phase A1: mid = relu(w1 @ x + b1), waves 0..3 (16 px each) ----
    if (w < 4) {
        int lpx = 16 * w + l16;
        int apy = lpx >> 3, apx = lpx & 7;
        const ushort_t* abase = xT + (size_t)((b * NH + h0 + apy) * NW + w0 + apx) * NC + quad * 8;
        floatx4 am0 = (floatx4)0.f, am1 = (floatx4)0.f;
#pragma unroll
        for (int kb = 0; kb < 4; kb++) {
            short8 a   = *(const short8*)(abase + kb * 32);
            short8 b0  = *(const short8*)(w1b + (l16) * NC + kb * 32 + quad * 8);
            short8 b1v = *(const short8*)(w1b + (16 + l16) * NC + kb * 32 + quad * 8);
            am0 = __builtin_amdgcn_mfma_f32_16x16x32_bf16(a, b0, am0, 0, 0, 0);
            am1 = __builtin_amdgcn_mfma_f32_16x16x32_bf16(a, b1v, am1, 0, 0, 0);
        }
        float bia0 = b1f[l16], bia1 = b1f[16 + l16];
#pragma unroll
        for (int r = 0; r < 4; r++) {
            int m = 16 * w + quad * 4 + r;
            midbuf[m * 32 + l16]      = f2bf(fmaxf(am0[r] + bia0, 0.f));
            midbuf[m * 32 + 16 + l16] = f2bf(fmaxf(am1[r] + bia1, 0.f));
        }
    }
    __syncthreads();

    // ---- Phase A2: wk = w2 @ mid + b2 -> wkstage[n][px] (8 waves) ----
    {
        short8 aM = *(const short8*)(midbuf + (16 * w4 + l16) * 32 + quad * 8);
        int nt0 = (w < 4) ? 0 : 13;
        int nt1 = (w < 4) ? 13 : 25;
        for (int nt = nt0; nt < nt1; nt++) {
            int n = nt * 16 + l16;
            short8 bw = *(const short8*)(w2b + n * 32 + quad * 8);
            floatx4 c = __builtin_amdgcn_mfma_f32_16x16x32_bf16(aM, bw, (floatx4)0.f, 0, 0, 0);
            float bias = b2f[n];
#pragma unroll
            for (int r = 0; r < 4; r++)
                wkstage[n * 66 + 16 * w4 + quad * 4 + r] = f2bf(c[r] + bias);
        }
    }
    __syncthreads();

    // ---- wk preload: lane (gg=t>>5, pp=t&31) handles px pair; group
    // g = gg>>1 = w. One u32 per tap packs (px0, px1). Wave-uniform row ->
    // broadcast read, conflict-free. 49 regs. ----
    int gg = t >> 5, pp = t & 31;
    int py = pp >> 2, ppx = pp & 3;
    int px0 = py * 8 + 2 * ppx;
    uint_t wkp[49];
#pragma unroll
    for (int k = 0; k < NKK; k++)
        wkp[k] = *(const uint_t*)&wkstage[(w * NKK + k) * 66 + px0];
    __syncthreads();        // all wk reads complete before LDS reuse

    // ---- Halo staging into x8 (overwrites wkstage; LINEAR layout) ----
    for (int it = 0; it < 7; it++) {
        int idx = it * 512 + t;
        if (idx < 3136) {
            int oct = idx & 15, hp = idx >> 4;
            int hy = hp / 14, hx = hp - hy * 14;
            int gh = h0 + hy - 3, gw = w0 + hx - 3;
            uint4 v = make_uint4(0u, 0u, 0u, 0u);
            if ((unsigned)gh < (unsigned)NH && (unsigned)gw < (unsigned)NW) {
                v = *(const uint4*)&xT[(size_t)((b * NH + gh) * NW + gw) * NC + 8 * oct];
            }
            x8[oct * 197 + hp] = v;
        }
    }
    __syncthreads();

    // ---- Phase B: involution; shared reads across the px pair ----
    floatx2 a0[4], a1[4];
#pragma unroll
    for (int j = 0; j < 4; j++) { a0[j] = (floatx2)0.f; a1[j] = (floatx2)0.f; }

#pragma unroll
    for (int dy = 0; dy < 7; dy++) {
        int xabase = (py + dy) * 14 + 2 * ppx;
#pragma unroll
        for (int m = 0; m < 8; m++) {
            uint4 u = x8[gg * 197 + xabase + m];
            floatx2 c0 = up2(u.x), c1 = up2(u.y), c2 = up2(u.z), c3 = up2(u.w);
            if (m < 7) {
                floatx2 wv = (floatx2)bf2f((ushort_t)(wkp[dy * 7 + m] & 0xffffu));
                a0[0] = wv * c0 + a0[0];
                a0[1] = wv * c1 + a0[1];
                a0[2] = wv * c2 + a0[2];
                a0[3] = wv * c3 + a0[3];
            }
            if (m > 0) {
                floatx2 wv = (floatx2)bf2f((ushort_t)(wkp[dy * 7 + m - 1] >> 16));
                a1[0] = wv * c0 + a1[0];
                a1[1] = wv * c1 + a1[1];
                a1[2] = wv * c2 + a1[2];
                a1[3] = wv * c3 + a1[3];
            }
        }
    }
    __syncthreads();

    // ---- LN1 over 128 ch: 8-ch partials, shfl_xor(32) pairs gg, then
    // 8-wave LDS reduce (stride-5 pad -> conflict-free) ----
    float s0 = 0.f, q0 = 0.f, s1 = 0.f, q1 = 0.f;
#pragma unroll
    for (int j = 0; j < 4; j++) {
        float v00 = a0[j][0], v01 = a0[j][1];
        float v10 = a1[j][0], v11 = a1[j][1];
        s0 += v00; q0 += v00 * v00; s0 += v01; q0 += v01 * v01;
        s1 += v10; q1 += v10 * v10; s1 += v11; q1 += v11 * v11;
    }
    s0 += __shfl_xor(s0, 32); q0 += __shfl_xor(q0, 32);
    s1 += __shfl_xor(s1, 32); q1 += __shfl_xor(q1, 32);
    float* sred = (float*)smem;
    if ((t & 32) == 0) {
        float* sp = sred + (w * 32 + pp) * 5;
        sp[0] = s0; sp[1] = q0; sp[2] = s1; sp[3] = q1;
    }
    __syncthreads();
    float ts0 = 0.f, tq0 = 0.f, ts1 = 0.f, tq1 = 0.f;
#pragma unroll
    for (int r = 0; r < 8; r++) {
        const float* sp = sred + (r * 32 + pp) * 5;
        ts0 += sp[0]; tq0 += sp[1]; ts1 += sp[2]; tq1 += sp[3];
    }
    float mean0 = ts0 * (1.0f / NC);
    float rstd0 = rsqrtf(tq0 * (1.0f / NC) - mean0 * mean0 + LN_EPS);
    float mean1 = ts1 * (1.0f / NC);
    float rstd1 = rsqrtf(tq1 * (1.0f / NC) - mean1 * mean1 + LN_EPS);

    // ---- gelu + pack + store (both px, 8 ch each) ----
    int pg = (b * NH + h0 + py) * NW + w0 + 2 * ppx;
    uint_t pk0[4], pk1[4];
#pragma unroll
    for (int j = 0; j < 4; j++) {
        int c0i = gg * 8 + 2 * j;
        float w0f = ln1wf[c0i], w1f = ln1wf[c0i + 1];
        float b0f = ln1bf[c0i], b1f_ = ln1bf[c0i + 1];
        float g00 = gelu_f((a0[j][0] - mean0) * rstd0 * w0f + b0f);
        float g01 = gelu_f((a0[j][1] - mean0) * rstd0 * w1f + b1f_);
        float g10 = gelu_f((a1[j][0] - mean1) * rstd1 * w0f + b0f);
        float g11 = gelu_f((a1[j][1] - mean1) * rstd1 * w1f + b1f_);
        pk0[j] = (uint_t)f2bf(g00) | ((uint_t)f2bf(g01) << 16);
        pk1[j] = (uint_t)f2bf(g10) | ((uint_t)f2bf(g11) << 16);
    }
    *(uint4*)&y1[(size_t)pg * NC + gg * 8]       = *(uint4*)pk0;
    *(uint4*)&y1[(size_t)(pg + 1) * NC + gg * 8] = *(uint4*)pk1;
}

// ---------------------------------------------------------------------------
// K23 v10 (unchanged). o-half split wave pairs; LDS-staged B via
// global_load_lds; streaming epilogue; 64 VGPR + 64 AGPR, no spill.
// grid 2048, block 256.
// ---------------------------------------------------------------------------
__global__ __launch_bounds__(256, 4) void k23(const void* __restrict__ x,
                                              const ushort_t* __restrict__ y1,
                                              const ushort_t* __restrict__ xT,
                                              const ushort_t* __restrict__ wfrag,
                                              const float* __restrict__ mbf,
                                              const float* __restrict__ ln2wf,
                                              const float* __restrict__ ln2bf,
                                              const float* __restrict__ ln3wf,
                                              const float* __restrict__ ln3bf,
                                              void* __restrict__ out) {
    __shared__ __align__(16) char sbuf[32768];   // B stage, reused for stats
    __shared__ int lf;
    int isf32 = sniff_isf32(x, &lf);

    int t = threadIdx.x;
    int lane = t & 63;
    int w = __builtin_amdgcn_readfirstlane(t >> 6);   // 0..3
    int quad = lane >> 4, l16 = lane & 15;
    int pair = w >> 1;                                // 0..1 -> px group
    int oh   = w & 1;                                 // 0..1 -> o-half (128 o's)

    int P0 = blockIdx.x * 32;
    int pw = P0 + pair * 16;                          // this wave's first pixel
    const ushort_t* aYp = y1 + (size_t)(pw + l16) * NC + quad * 8;
    const ushort_t* aXp = xT + (size_t)(pw + l16) * NC + quad * 8;

    // stage kb=0 B-tile (32KB): wave w covers chunks [w*512, w*512+512)
    {
        const ushort_t* gsrc = wfrag + (size_t)(w * 512 + lane) * 8;
        char* ldst = sbuf + (size_t)(w * 512) * 16;
#pragma unroll
        for (int i = 0; i < 8; i++)
            gload_lds16(gsrc + i * 64 * 8, ldst + i * 64 * 16);
    }
    // A operands (both branches) for all 4 k-blocks, hoisted to registers
    short8 Ay[4], Ax[4];
#pragma unroll
    for (int kb = 0; kb < 4; kb++) {
        Ay[kb] = *(const short8*)(aYp + kb * 32);
        Ax[kb] = *(const short8*)(aXp + kb * 32);
    }
    __syncthreads();

    floatx4 accC[8], accM[8];
#pragma unroll
    for (int j = 0; j < 8; j++) { accC[j] = (floatx4)0.f; accM[j] = (floatx4)0.f; }

#pragma unroll
    for (int kb = 0; kb < 4; kb++) {
        short8 ay = Ay[kb], ax = Ax[kb];
#pragma unroll
        for (int j = 0; j < 8; j++) {
            int n4 = oh * 8 + j;
            // tile layout: [br:1][n4:4][lane:6] chunks of 16 B
            short8 bc = *(const short8*)(sbuf + (size_t)(n4 * 64 + lane) * 16);
            short8 bm = *(const short8*)(sbuf + 16384 + (size_t)(n4 * 64 + lane) * 16);
            accC[j] = __builtin_amdgcn_mfma_f32_16x16x32_bf16(ay, bc, accC[j], 0, 0, 0);
            accM[j] = __builtin_amdgcn_mfma_f32_16x16x32_bf16(ax, bm, accM[j], 0, 0, 0);
        }
        __syncthreads();                              // all B reads done
        if (kb < 3) {
            const ushort_t* gsrc = wfrag + ((size_t)(kb + 1) * 2048 + w * 512 + lane) * 8;
            char* ldst = sbuf + (size_t)(w * 512) * 16;
#pragma unroll
            for (int i = 0; i < 8; i++)
                gload_lds16(gsrc + i * 64 * 8, ldst + i * 64 * 16);
            __syncthreads();                          // staging visible (vmcnt drained)
        }
    }

    // map-branch bias (before LN3 stats)
#pragma unroll
    for (int j = 0; j < 8; j++) {
        float mb = mbf[(oh * 8 + j) * 16 + l16];
#pragma unroll
        for (int r = 0; r < 4; r++) accM[j][r] += mb;
    }

    // LN partial stats per px (px = quad*4 + r) over this wave's 128 o's
    floatx4 s1 = (floatx4)0.f, q1 = (floatx4)0.f, s2 = (floatx4)0.f, q2 = (floatx4)0.f;
#pragma unroll
    for (int j = 0; j < 8; j++)
#pragma unroll
        for (int r = 0; r < 4; r++) {
            float a = accC[j][r], m = accM[j][r];
            s1[r] += a; q1[r] += a * a;
            s2[r] += m; q2[r] += m * m;
        }
#pragma unroll
    for (int d = 1; d < 16; d <<= 1) {
#pragma unroll
        for (int r = 0; r < 4; r++) {
            s1[r] += __shfl_xor(s1[r], d);
            q1[r] += __shfl_xor(q1[r], d);
            s2[r] += __shfl_xor(s2[r], d);
            q2[r] += __shfl_xor(q2[r], d);
        }
    }

    // exchange partial stats with the pair's other o-half through sbuf (dead)
    float* sstat = (float*)sbuf;
    if (l16 == 0) {
#pragma unroll
        for (int r = 0; r < 4; r++) {
            float* sp = sstat + (((pair * 2 + oh) * 16) + quad * 4 + r) * 4;
            sp[0] = s1[r]; sp[1] = q1[r]; sp[2] = s2[r]; sp[3] = q2[r];
        }
    }
    __syncthreads();

    floatx4 mn1, rs1, mn2, rs2;
#pragma unroll
    for (int r = 0; r < 4; r++) {
        const float* op = sstat + (((pair * 2 + (oh ^ 1)) * 16) + quad * 4 + r) * 4;
        float S1 = s1[r] + op[0], Q1 = q1[r] + op[1];
        float S2 = s2[r] + op[2], Q2 = q2[r] + op[3];
        mn1[r] = S1 * (1.0f / NO);
        rs1[r] = rsqrtf(Q1 * (1.0f / NO) - mn1[r] * mn1[r] + LN_EPS);
        mn2[r] = S2 * (1.0f / NO);
        rs2[r] = rsqrtf(Q2 * (1.0f / NO) - mn2[r] * mn2[r] + LN_EPS);
    }

    // streaming epilogue: per n4, normalize both branches, gelu, direct store
    int batch = pw >> 14;
    int plocal = (pw & 16383) + quad * 4;
#pragma unroll
    for (int j = 0; j < 8; j++) {
        int o = (oh * 8 + j) * 16 + l16;
        float l2w = ln2wf[o], l2b = ln2bf[o];
        float l3w = ln3wf[o], l3b = ln3bf[o];
        float4 gv;
        {
            float v1, v2;
            v1 = (accC[j][0] - mn1[0]) * rs1[0] * l2w + l2b;
            v2 = (accM[j][0] - mn2[0]) * rs2[0] * l3w + l3b;
            gv.x = gelu_f(v1 + v2);
            v1 = (accC[j][1] - mn1[1]) * rs1[1] * l2w + l2b;
            v2 = (accM[j][1] - mn2[1]) * rs2[1] * l3w + l3b;
            gv.y = gelu_f(v1 + v2);
            v1 = (accC[j][2] - mn1[2]) * rs1[2] * l2w + l2b;
            v2 = (accM[j][2] - mn2[2]) * rs2[2] * l3w + l3b;
            gv.z = gelu_f(v1 + v2);
            v1 = (accC[j][3] - mn1[3]) * rs1[3] * l2w + l2b;
            v2 = (accM[j][3] - mn2[3]) * rs2[3] * l3w + l3b;
            gv.w = gelu_f(v1 + v2);
        }
        size_t oi = ((size_t)(batch * NO + o) << 14) + plocal;
        if (isf32) {
            *(float4*)((float*)out + oi) = gv;
        } else {
            uint_t p0 = (uint_t)f2bf(gv.x) | ((uint_t)f2bf(gv.y) << 16);
            uint_t p1 = (uint_t)f2bf(gv.z) | ((uint_t)f2bf(gv.w) << 16);
            *(uint2*)((ushort_t*)out + oi) = make_uint2(p0, p1);
        }
    }
}

// ---------------------------------------------------------------------------
extern "C" void kernel_launch(void* const* d_in, const int* in_sizes, int n_in,
                              void* d_out, int out_size, void* d_ws, size_t ws_size,
                              hipStream_t stream) {
    const void* x      = d_in[0];
    const void* w1     = d_in[1];
    const void* b1     = d_in[2];
    const void* w2     = d_in[3];
    const void* b2     = d_in[4];
    const void* ln1w   = d_in[5];
    const void* ln1b   = d_in[6];
    const void* conv_w = d_in[7];
    const void* ln2w   = d_in[8];
    const void* ln2b   = d_in[9];
    const void* map_w  = d_in[10];
    const void* map_b  = d_in[11];
    const void* ln3w   = d_in[12];
    const void* ln3b   = d_in[13];

    char* ws = (char*)d_ws;
    ushort_t* xT    = (ushort_t*)(ws);                  // 16,777,216 B
    ushort_t* y1    = (ushort_t*)(ws + 16777216);       // 16,777,216 B
    ushort_t* wfrag = (ushort_t*)(ws + 33554432);       // 131,072 B
    ushort_t* w1b   = (ushort_t*)(ws + 33685504);       //   8,192 B
    ushort_t* w2b   = (ushort_t*)(ws + 33693696);       //  25,600 B
    float*    b1f   = (float*)(ws + 33719296);
    float*    b2f   = (float*)(ws + 33719424);
    float*    ln1wf = (float*)(ws + 33721024);
    float*    ln1bf = (float*)(ws + 33721536);
    float*    mbf   = (float*)(ws + 33722048);
    float*    ln2wf = (float*)(ws + 33723072);
    float*    ln2bf = (float*)(ws + 33724096);
    float*    ln3wf = (float*)(ws + 33725120);
    float*    ln3bf = (float*)(ws + 33726144);
    const size_t NEED_SMALL = 33727184;

    if (ws_size < NEED_SMALL) {
        int nwords = out_size / 2;
        ksentinel<<<(nwords + 255) / 256, 256, 0, stream>>>((uint_t*)d_out, nwords);
        return;
    }

    kpf<<<4256, 256, 0, stream>>>(x, w1, w2, b1, b2, ln1w, ln1b,
                                  ln2w, ln2b, map_b, ln3w, ln3b,
                                  conv_w, map_w, xT,
                                  w1b, w2b, b1f, b2f, ln1wf, ln1bf,
                                  ln2wf, ln2bf, mbf, ln3wf, ln3bf, wfrag);
    k1f<<<1024, 512, 0, stream>>>(xT, w1b, b1f, w2b, b2f, ln1wf, ln1bf, y1);
    k23<<<NPIX / 32, 256, 0, stream>>>(x, y1, xT, wfrag, mbf,
                                       ln2wf, ln2bf, ln3wf, ln3bf, d_out);
}

// Round 15
// 195.665 us; speedup vs baseline: 1.1421x; 1.0055x over previous
//
#include <hip/hip_runtime.h>

typedef unsigned short ushort_t;
typedef unsigned int uint_t;

#define NB 4
#define NC 128
#define NH 128
#define NW 128
#define NPIX 65536   // NB*NH*NW
#define NMID 32
#define NKK 49
#define NK 392
#define NKP 400      // NK padded to 25 n-tiles of 16
#define NO 256
#define LN_EPS 1e-6f

typedef __attribute__((ext_vector_type(8))) short short8;
typedef __attribute__((ext_vector_type(4))) float floatx4;
typedef __attribute__((ext_vector_type(2))) float floatx2;

__device__ __forceinline__ float bf2f(ushort_t u) {
    union { uint_t i; float f; } v; v.i = ((uint_t)u) << 16; return v.f;
}
__device__ __forceinline__ float bf2f_lo(uint_t u) {
    union { uint_t i; float f; } v; v.i = u << 16; return v.f;
}
__device__ __forceinline__ float bf2f_hi(uint_t u) {
    union { uint_t i; float f; } v; v.i = u & 0xffff0000u; return v.f;
}
// unpack a packed bf16 pair -> floatx2 {lo, hi}
__device__ __forceinline__ floatx2 up2(uint_t u) {
    union { uint_t i; float f; } lo, hi;
    lo.i = u << 16; hi.i = u & 0xffff0000u;
    floatx2 r; r[0] = lo.f; r[1] = hi.f; return r;
}
__device__ __forceinline__ ushort_t f2bf(float f) {
    union { float f; uint_t i; } v; v.f = f;
    uint_t x = v.i;
    uint_t r = (x + 0x7FFFu + ((x >> 16) & 1u)) >> 16;
    return (ushort_t)r;
}
__device__ __forceinline__ float gelu_f(float x) {
    return 0.5f * x * (1.0f + erff(x * 0.70710678118654752f));
}
__device__ __forceinline__ float ldin(const void* p, int i, int isf32) {
    return isf32 ? ((const float*)p)[i] : bf2f(((const ushort_t*)p)[i]);
}
// global -> LDS direct DMA, 16B per lane; LDS dest = uniform base + lane*16
__device__ __forceinline__ void gload_lds16(const void* g, void* l) {
    __builtin_amdgcn_global_load_lds(
        (const __attribute__((address_space(1))) void*)g,
        (__attribute__((address_space(3))) void*)l, 16, 0, 0);
}

// ---------------------------------------------------------------------------
// Per-block dtype sniff (in_sizes are ELEMENT counts — r8 post-mortem — so
// runtime sniffing is required). One wave computes, broadcast via LDS.
// ---------------------------------------------------------------------------
__device__ __forceinline__ int sniff_isf32(const void* x, int* lf) {
    int t = threadIdx.x;
    if (t < 64) {
        const uint_t* xw = (const uint_t*)x;
        int cnt = 0;
#pragma unroll
        for (int j = 0; j < 8; j++) {
            uint_t wv = xw[t * 8 + j];
            uint_t e = (wv >> 7) & 0xffu;
            if (e >= 110u && e <= 135u) cnt++;
        }
#pragma unroll
        for (int d = 1; d < 64; d <<= 1) cnt += __shfl_xor(cnt, d);
        if (t == 0) *lf = (cnt < 256) ? 1 : 0;
    }
    __syncthreads();
    return *lf;
}

__global__ void ksentinel(uint_t* __restrict__ out, int nwords) {
    int i = blockIdx.x * 256 + threadIdx.x;
    if (i < nwords) out[i] = 0x40004000u;
}

// ---------------------------------------------------------------------------
// KPF: merged transpose + param-prep + fragment repack (3-dispatch pipeline).
// Blocks [0,4096): ktrans v3 body. Blocks [4096,4224): param prep.
// Blocks [4224,4256): conv/map frag repack (cid = [kb:2][br:1][n4:4][lane:6]
// chunks of 8 bf16; kb-tiles contiguous -> linear global_load_lds in k23).
// grid 4256, block 256.
// ---------------------------------------------------------------------------
__global__ __launch_bounds__(256) void kpf(const void* x,
                                           const void* w1, const void* w2,
                                           const void* b1, const void* b2,
                                           const void* ln1w, const void* ln1b,
                                           const void* ln2w, const void* ln2b,
                                           const void* map_b,
                                           const void* ln3w, const void* ln3b,
                                           const void* conv_w, const void* map_w,
                                           ushort_t* __restrict__ xT,
                                           ushort_t* __restrict__ w1b,
                                           ushort_t* __restrict__ w2b,
                                           float* __restrict__ b1f,
                                           float* __restrict__ b2f,
                                           float* __restrict__ ln1wf,
                                           float* __restrict__ ln1bf,
                                           float* __restrict__ ln2wf,
                                           float* __restrict__ ln2bf,
                                           float* __restrict__ mbf,
                                           float* __restrict__ ln3wf,
                                           float* __restrict__ ln3bf,
                                           ushort_t* __restrict__ wfrag) {
    __shared__ __align__(16) ushort_t tile[32][72];
    __shared__ int lf;
    int isf32 = sniff_isf32(x, &lf);
    int bid = blockIdx.x;
    int t = threadIdx.x;

    if (bid < 4096) {
        int b = bid >> 10, h = (bid >> 3) & 127;
        int wchunk = bid & 1, cchunk = (bid >> 1) & 3;
        int w0 = wchunk << 6, c0 = cchunk << 5;
        {
            int cc = t >> 3, wseg = t & 7;
            size_t idx = (size_t)((b * NC + c0 + cc) * NH + h) * NW + w0 + wseg * 8;
            uint4 pk;
            if (isf32) {
                float4 f0 = *(const float4*)((const float*)x + idx);
                float4 f1 = *(const float4*)((const float*)x + idx + 4);
                pk.x = (uint_t)f2bf(f0.x) | ((uint_t)f2bf(f0.y) << 16);
                pk.y = (uint_t)f2bf(f0.z) | ((uint_t)f2bf(f0.w) << 16);
                pk.z = (uint_t)f2bf(f1.x) | ((uint_t)f2bf(f1.y) << 16);
                pk.w = (uint_t)f2bf(f1.z) | ((uint_t)f2bf(f1.w) << 16);
            } else {
                pk = *(const uint4*)((const ushort_t*)x + idx);
            }
            *(uint4*)&tile[cc][wseg * 8] = pk;
        }
        __syncthreads();
        int px = t >> 2, seg = t & 3;
        ushort_t o[8];
#pragma unroll
        for (int j = 0; j < 8; j++) o[j] = tile[seg * 8 + j][px];
        *(uint4*)&xT[((size_t)((b * NH + h) * NW) + w0 + px) * NC + c0 + seg * 8]
            = *(uint4*)o;
    } else if (bid < 4224) {
        int i = (bid - 4096) * 256 + t;
        if (i < NMID * NC) w1b[i] = f2bf(ldin(w1, i, isf32));
        if (i < NKP * NMID) w2b[i] = (i < NK * NMID) ? f2bf(ldin(w2, i, isf32))
                                                     : (ushort_t)0;
        if (i < NMID) b1f[i] = ldin(b1, i, isf32);
        if (i < NKP)  b2f[i] = (i < NK) ? ldin(b2, i, isf32) : 0.f;
        if (i < NC) { ln1wf[i] = ldin(ln1w, i, isf32); ln1bf[i] = ldin(ln1b, i, isf32); }
        if (i < NO) {
            ln2wf[i] = ldin(ln2w, i, isf32); ln2bf[i] = ldin(ln2b, i, isf32);
            mbf[i]   = ldin(map_b, i, isf32);
            ln3wf[i] = ldin(ln3w, i, isf32); ln3bf[i] = ldin(ln3b, i, isf32);
        }
    } else {
        int cid = (bid - 4224) * 256 + t;   // [0, 8192)
        int lane = cid & 63, n4 = (cid >> 6) & 15, br = (cid >> 10) & 1, kb = cid >> 11;
        int o = n4 * 16 + (lane & 15);
        int ch0 = kb * 32 + (lane >> 4) * 8;
        const void* src = br ? map_w : conv_w;
        ushort_t* dst = wfrag + (size_t)cid * 8;
#pragma unroll
        for (int j = 0; j < 8; j++)
            dst[j] = f2bf(ldin(src, o * NC + ch0 + j, isf32));
    }
}

// ---------------------------------------------------------------------------
// K1F v6 (unchanged from round 14): phase B with 2-adjacent-px per lane,
// shared halo reads, packed v2f32 fma. Block 512, grid 1024.
// ---------------------------------------------------------------------------
__global__ __launch_bounds__(512) void k1f(const ushort_t* __restrict__ xT,
                                           const ushort_t* __restrict__ w1b,
                                           const float* __restrict__ b1f,
                                           const ushort_t* __restrict__ w2b,
                                           const float* __restrict__ b2f,
                                           const float* __restrict__ ln1wf,
                                           const float* __restrict__ ln1bf,
                                           ushort_t* __restrict__ y1) {
    __shared__ __align__(16) char smem[52800];   // wkstage, then x8/sred
    __shared__ ushort_t midbuf[64 * 32];
    ushort_t* wkstage = (ushort_t*)smem;
    uint4*    x8      = (uint4*)smem;

    int t = threadIdx.x;
    int lane = t & 63;
    int w = __builtin_amdgcn_readfirstlane(t >> 6);   // 0..7
    int l16 = lane & 15, quad = lane >> 4;
    int tileid = blockIdx.x;
    int tilex = tileid & 15, tiley = (tileid >> 4) & 15, b = tileid >> 8;
    int h0 = tiley * 8, w0 = tilex * 8;
    int w4 = w & 3;

    // ---- Phase A1: mid = relu(w1 @ x + b1), waves 0..3 (16 px each) ----
    if (w < 4) {
        int lpx = 16 * w + l16;
        int apy = lpx >> 3, apx = lpx & 7;
        const ushort_t* abase = xT + (size_t)((b * NH + h0 + apy) * NW + w0 + apx) * NC + quad * 8;
        floatx4 am0 = (floatx4)0.f, am1 = (floatx4)0.f;
#pragma unroll
        for (int kb = 0; kb < 4; kb++) {
            short8 a   = *(const short8*)(abase + kb * 32);
            short8 b0  = *(const short8*)(w1b + (l16) * NC + kb * 32 + quad * 8);
            short8 b1v = *(const short8*)(w1b + (16 + l16) * NC + kb * 32 + quad * 8);
            am0 = __builtin_amdgcn_mfma_f32_16x16x32_bf16(a, b0, am0, 0, 0, 0);
            am1 = __builtin_amdgcn_mfma_f32_16x16x32_bf16(a, b1v, am1, 0, 0, 0);
        }
        float bia0 = b1f[l16], bia1 = b1f[16 + l16];
#pragma unroll
        for (int r = 0; r < 4; r++) {
            int m = 16 * w + quad * 4 + r;
            midbuf[m * 32 + l16]      = f2bf(fmaxf(am0[r] + bia0, 0.f));
            midbuf[m * 32 + 16 + l16] = f2bf(fmaxf(am1[r] + bia1, 0.f));
        }
    }
    __syncthreads();

    // ---- Phase A2: wk = w2 @ mid + b2 -> wkstage[n][px] (8 waves) ----
    {
        short8 aM = *(const short8*)(midbuf + (16 * w4 + l16) * 32 + quad * 8);
        int nt0 = (w < 4) ? 0 : 13;
        int nt1 = (w < 4) ? 13 : 25;
        for (int nt = nt0; nt < nt1; nt++) {
            int n = nt * 16 + l16;
            short8 bw = *(const short8*)(w2b + n * 32 + quad * 8);
            floatx4 c = __builtin_amdgcn_mfma_f32_16x16x32_bf16(aM, bw, (floatx4)0.f, 0, 0, 0);
            float bias = b2f[n];
#pragma unroll
            for (int r = 0; r < 4; r++)
                wkstage[n * 66 + 16 * w4 + quad * 4 + r] = f2bf(c[r] + bias);
        }
    }
    __syncthreads();

    // ---- wk preload: lane (gg=t>>5, pp=t&31) handles px pair; one u32 per
    // tap packs (px0, px1). Wave-uniform row -> broadcast, conflict-free. ----
    int gg = t >> 5, pp = t & 31;
    int py = pp >> 2, ppx = pp & 3;
    int px0 = py * 8 + 2 * ppx;
    uint_t wkp[49];
#pragma unroll
    for (int k = 0; k < NKK; k++)
        wkp[k] = *(const uint_t*)&wkstage[(w * NKK + k) * 66 + px0];
    __syncthreads();        // all wk reads complete before LDS reuse

    // ---- Halo staging into x8 (overwrites wkstage; LINEAR layout) ----
    for (int it = 0; it < 7; it++) {
        int idx = it * 512 + t;
        if (idx < 3136) {
            int oct = idx & 15, hp = idx >> 4;
            int hy = hp / 14, hx = hp - hy * 14;
            int gh = h0 + hy - 3, gw = w0 + hx - 3;
            uint4 v = make_uint4(0u, 0u, 0u, 0u);
            if ((unsigned)gh < (unsigned)NH && (unsigned)gw < (unsigned)NW) {
                v = *(const uint4*)&xT[(size_t)((b * NH + gh) * NW + gw) * NC + 8 * oct];
            }
            x8[oct * 197 + hp] = v;
        }
    }
    __syncthreads();

    // ---- Phase B: involution; shared reads across the px pair ----
    floatx2 a0[4], a1[4];
#pragma unroll
    for (int j = 0; j < 4; j++) { a0[j] = (floatx2)0.f; a1[j] = (floatx2)0.f; }

#pragma unroll
    for (int dy = 0; dy < 7; dy++) {
        int xabase = (py + dy) * 14 + 2 * ppx;
#pragma unroll
        for (int m = 0; m < 8; m++) {
            uint4 u = x8[gg * 197 + xabase + m];
            floatx2 c0 = up2(u.x), c1 = up2(u.y), c2 = up2(u.z), c3 = up2(u.w);
            if (m < 7) {
                floatx2 wv = (floatx2)bf2f((ushort_t)(wkp[dy * 7 + m] & 0xffffu));
                a0[0] = wv * c0 + a0[0];
                a0[1] = wv * c1 + a0[1];
                a0[2] = wv * c2 + a0[2];
                a0[3] = wv * c3 + a0[3];
            }
            if (m > 0) {
                floatx2 wv = (floatx2)bf2f((ushort_t)(wkp[dy * 7 + m - 1] >> 16));
                a1[0] = wv * c0 + a1[0];
                a1[1] = wv * c1 + a1[1];
                a1[2] = wv * c2 + a1[2];
                a1[3] = wv * c3 + a1[3];
            }
        }
    }
    __syncthreads();

    // ---- LN1 over 128 ch: 8-ch partials, shfl_xor(32) pairs gg, then
    // 8-wave LDS reduce (stride-5 pad -> conflict-free) ----
    float s0 = 0.f, q0 = 0.f, s1 = 0.f, q1 = 0.f;
#pragma unroll
    for (int j = 0; j < 4; j++) {
        float v00 = a0[j][0], v01 = a0[j][1];
        float v10 = a1[j][0], v11 = a1[j][1];
        s0 += v00; q0 += v00 * v00; s0 += v01; q0 += v01 * v01;
        s1 += v10; q1 += v10 * v10; s1 += v11; q1 += v11 * v11;
    }
    s0 += __shfl_xor(s0, 32); q0 += __shfl_xor(q0, 32);
    s1 += __shfl_xor(s1, 32); q1 += __shfl_xor(q1, 32);
    float* sred = (float*)smem;
    if ((t & 32) == 0) {
        float* sp = sred + (w * 32 + pp) * 5;
        sp[0] = s0; sp[1] = q0; sp[2] = s1; sp[3] = q1;
    }
    __syncthreads();
    float ts0 = 0.f, tq0 = 0.f, ts1 = 0.f, tq1 = 0.f;
#pragma unroll
    for (int r = 0; r < 8; r++) {
        const float* sp = sred + (r * 32 + pp) * 5;
        ts0 += sp[0]; tq0 += sp[1]; ts1 += sp[2]; tq1 += sp[3];
    }
    float mean0 = ts0 * (1.0f / NC);
    float rstd0 = rsqrtf(tq0 * (1.0f / NC) - mean0 * mean0 + LN_EPS);
    float mean1 = ts1 * (1.0f / NC);
    float rstd1 = rsqrtf(tq1 * (1.0f / NC) - mean1 * mean1 + LN_EPS);

    // ---- gelu + pack + store (both px, 8 ch each) ----
    int pg = (b * NH + h0 + py) * NW + w0 + 2 * ppx;
    uint_t pk0[4], pk1[4];
#pragma unroll
    for (int j = 0; j < 4; j++) {
        int c0i = gg * 8 + 2 * j;
        float w0f = ln1wf[c0i], w1f = ln1wf[c0i + 1];
        float b0f = ln1bf[c0i], b1f_ = ln1bf[c0i + 1];
        float g00 = gelu_f((a0[j][0] - mean0) * rstd0 * w0f + b0f);
        float g01 = gelu_f((a0[j][1] - mean0) * rstd0 * w1f + b1f_);
        float g10 = gelu_f((a1[j][0] - mean1) * rstd1 * w0f + b0f);
        float g11 = gelu_f((a1[j][1] - mean1) * rstd1 * w1f + b1f_);
        pk0[j] = (uint_t)f2bf(g00) | ((uint_t)f2bf(g01) << 16);
        pk1[j] = (uint_t)f2bf(g10) | ((uint_t)f2bf(g11) << 16);
    }
    *(uint4*)&y1[(size_t)pg * NC + gg * 8]       = *(uint4*)pk0;
    *(uint4*)&y1[(size_t)(pg + 1) * NC + gg * 8] = *(uint4*)pk1;
}

// ---------------------------------------------------------------------------
// K23 v11: 64 px/block (block 512 = 4 pairs x 2 o-halves, grid 1024).
// Per-wave MFMA/acc/LN/epilogue identical to v10 (16 px x 128 o, 64 VGPR +
// 64 AGPR); but the per-block 128KB B-staging is now amortized over 2x the
// pixels: staging issues/wave halve (8->4 per kb), total B LDS traffic
// halves, barriers-per-pixel halve (r14: staging+8-barrier-drain per 32 px
// was the remaining structural cost; m97 barrier-drain effect).
// __launch_bounds__(512,4) keeps the 128-reg budget -> 2 blocks/CU,
// 16 waves/CU cap (same as v10). Stats exchange 2KB in dead sbuf.
// ---------------------------------------------------------------------------
__global__ __launch_bounds__(512, 4) void k23(const void* __restrict__ x,
                                              const ushort_t* __restrict__ y1,
                                              const ushort_t* __restrict__ xT,
                                              const ushort_t* __restrict__ wfrag,
                                              const float* __restrict__ mbf,
                                              const float* __restrict__ ln2wf,
                                              const float* __restrict__ ln2bf,
                                              const float* __restrict__ ln3wf,
                                              const float* __restrict__ ln3bf,
                                              void* __restrict__ out) {
    __shared__ __align__(16) char sbuf[32768];   // B stage, reused for stats
    __shared__ int lf;
    int isf32 = sniff_isf32(x, &lf);

    int t = threadIdx.x;
    int lane = t & 63;
    int w = __builtin_amdgcn_readfirstlane(t >> 6);   // 0..7
    int quad = lane >> 4, l16 = lane & 15;
    int pair = w >> 1;                                // 0..3 -> px group
    int oh   = w & 1;                                 // 0..1 -> o-half (128 o's)

    int P0 = blockIdx.x * 64;
    int pw = P0 + pair * 16;                          // this wave's first pixel
    const ushort_t* aYp = y1 + (size_t)(pw + l16) * NC + quad * 8;
    const ushort_t* aXp = xT + (size_t)(pw + l16) * NC + quad * 8;

    // stage kb=0 B-tile (32KB): wave w covers chunks [w*256, w*256+256)
    {
        const ushort_t* gsrc = wfrag + (size_t)(w * 256 + lane) * 8;
        char* ldst = sbuf + (size_t)(w * 256) * 16;
#pragma unroll
        for (int i = 0; i < 4; i++)
            gload_lds16(gsrc + i * 64 * 8, ldst + i * 64 * 16);
    }
    // A operands (both branches) for all 4 k-blocks, hoisted to registers
    short8 Ay[4], Ax[4];
#pragma unroll
    for (int kb = 0; kb < 4; kb++) {
        Ay[kb] = *(const short8*)(aYp + kb * 32);
        Ax[kb] = *(const short8*)(aXp + kb * 32);
    }
    __syncthreads();

    floatx4 accC[8], accM[8];
#pragma unroll
    for (int j = 0; j < 8; j++) { accC[j] = (floatx4)0.f; accM[j] = (floatx4)0.f; }

#pragma unroll
    for (int kb = 0; kb < 4; kb++) {
        short8 ay = Ay[kb], ax = Ax[kb];
#pragma unroll
        for (int j = 0; j < 8; j++) {
            int n4 = oh * 8 + j;
            // tile layout: [br:1][n4:4][lane:6] chunks of 16 B
            short8 bc = *(const short8*)(sbuf + (size_t)(n4 * 64 + lane) * 16);
            short8 bm = *(const short8*)(sbuf + 16384 + (size_t)(n4 * 64 + lane) * 16);
            accC[j] = __builtin_amdgcn_mfma_f32_16x16x32_bf16(ay, bc, accC[j], 0, 0, 0);
            accM[j] = __builtin_amdgcn_mfma_f32_16x16x32_bf16(ax, bm, accM[j], 0, 0, 0);
        }
        __syncthreads();                              // all B reads done
        if (kb < 3) {
            const ushort_t* gsrc = wfrag + ((size_t)(kb + 1) * 2048 + w * 256 + lane) * 8;
            char* ldst = sbuf + (size_t)(w * 256) * 16;
#pragma unroll
            for (int i = 0; i < 4; i++)
                gload_lds16(gsrc + i * 64 * 8, ldst + i * 64 * 16);
            __syncthreads();                          // staging visible (vmcnt drained)
        }
    }

    // map-branch bias (before LN3 stats)
#pragma unroll
    for (int j = 0; j < 8; j++) {
        float mb = mbf[(oh * 8 + j) * 16 + l16];
#pragma unroll
        for (int r = 0; r < 4; r++) accM[j][r] += mb;
    }

    // LN partial stats per px (px = quad*4 + r) over this wave's 128 o's
    floatx4 s1 = (floatx4)0.f, q1 = (floatx4)0.f, s2 = (floatx4)0.f, q2 = (floatx4)0.f;
#pragma unroll
    for (int j = 0; j < 8; j++)
#pragma unroll
        for (int r = 0; r < 4; r++) {
            float a = accC[j][r], m = accM[j][r];
            s1[r] += a; q1[r] += a * a;
            s2[r] += m; q2[r] += m * m;
        }
#pragma unroll
    for (int d = 1; d < 16; d <<= 1) {
#pragma unroll
        for (int r = 0; r < 4; r++) {
            s1[r] += __shfl_xor(s1[r], d);
            q1[r] += __shfl_xor(q1[r], d);
            s2[r] += __shfl_xor(s2[r], d);
            q2[r] += __shfl_xor(q2[r], d);
        }
    }

    // exchange partial stats with the pair's other o-half through sbuf (dead):
    // [pair:2][oh:1][px:4bits][4 stats] floats = 512 floats = 2 KB.
    float* sstat = (float*)sbuf;
    if (l16 == 0) {
#pragma unroll
        for (int r = 0; r < 4; r++) {
            float* sp = sstat + (((pair * 2 + oh) * 16) + quad * 4 + r) * 4;
            sp[0] = s1[r]; sp[1] = q1[r]; sp[2] = s2[r]; sp[3] = q2[r];
        }
    }
    __syncthreads();

    floatx4 mn1, rs1, mn2, rs2;
#pragma unroll
    for (int r = 0; r < 4; r++) {
        const float* op = sstat + (((pair * 2 + (oh ^ 1)) * 16) + quad * 4 + r) * 4;
        float S1 = s1[r] + op[0], Q1 = q1[r] + op[1];
        float S2 = s2[r] + op[2], Q2 = q2[r] + op[3];
        mn1[r] = S1 * (1.0f / NO);
        rs1[r] = rsqrtf(Q1 * (1.0f / NO) - mn1[r] * mn1[r] + LN_EPS);
        mn2[r] = S2 * (1.0f / NO);
        rs2[r] = rsqrtf(Q2 * (1.0f / NO) - mn2[r] * mn2[r] + LN_EPS);
    }

    // streaming epilogue: per n4, normalize both branches, gelu, direct store
    int batch = pw >> 14;
    int plocal = (pw & 16383) + quad * 4;
#pragma unroll
    for (int j = 0; j < 8; j++) {
        int o = (oh * 8 + j) * 16 + l16;
        float l2w = ln2wf[o], l2b = ln2bf[o];
        float l3w = ln3wf[o], l3b = ln3bf[o];
        float4 gv;
        {
            float v1, v2;
            v1 = (accC[j][0] - mn1[0]) * rs1[0] * l2w + l2b;
            v2 = (accM[j][0] - mn2[0]) * rs2[0] * l3w + l3b;
            gv.x = gelu_f(v1 + v2);
            v1 = (accC[j][1] - mn1[1]) * rs1[1] * l2w + l2b;
            v2 = (accM[j][1] - mn2[1]) * rs2[1] * l3w + l3b;
            gv.y = gelu_f(v1 + v2);
            v1 = (accC[j][2] - mn1[2]) * rs1[2] * l2w + l2b;
            v2 = (accM[j][2] - mn2[2]) * rs2[2] * l3w + l3b;
            gv.z = gelu_f(v1 + v2);
            v1 = (accC[j][3] - mn1[3]) * rs1[3] * l2w + l2b;
            v2 = (accM[j][3] - mn2[3]) * rs2[3] * l3w + l3b;
            gv.w = gelu_f(v1 + v2);
        }
        size_t oi = ((size_t)(batch * NO + o) << 14) + plocal;
        if (isf32) {
            *(float4*)((float*)out + oi) = gv;
        } else {
            uint_t p0 = (uint_t)f2bf(gv.x) | ((uint_t)f2bf(gv.y) << 16);
            uint_t p1 = (uint_t)f2bf(gv.z) | ((uint_t)f2bf(gv.w) << 16);
            *(uint2*)((ushort_t*)out + oi) = make_uint2(p0, p1);
        }
    }
}

// ---------------------------------------------------------------------------
extern "C" void kernel_launch(void* const* d_in, const int* in_sizes, int n_in,
                              void* d_out, int out_size, void* d_ws, size_t ws_size,
                              hipStream_t stream) {
    const void* x      = d_in[0];
    const void* w1     = d_in[1];
    const void* b1     = d_in[2];
    const void* w2     = d_in[3];
    const void* b2     = d_in[4];
    const void* ln1w   = d_in[5];
    const void* ln1b   = d_in[6];
    const void* conv_w = d_in[7];
    const void* ln2w   = d_in[8];
    const void* ln2b   = d_in[9];
    const void* map_w  = d_in[10];
    const void* map_b  = d_in[11];
    const void* ln3w   = d_in[12];
    const void* ln3b   = d_in[13];

    char* ws = (char*)d_ws;
    ushort_t* xT    = (ushort_t*)(ws);                  // 16,777,216 B
    ushort_t* y1    = (ushort_t*)(ws + 16777216);       // 16,777,216 B
    ushort_t* wfrag = (ushort_t*)(ws + 33554432);       // 131,072 B
    ushort_t* w1b   = (ushort_t*)(ws + 33685504);       //   8,192 B
    ushort_t* w2b   = (ushort_t*)(ws + 33693696);       //  25,600 B
    float*    b1f   = (float*)(ws + 33719296);
    float*    b2f   = (float*)(ws + 33719424);
    float*    ln1wf = (float*)(ws + 33721024);
    float*    ln1bf = (float*)(ws + 33721536);
    float*    mbf   = (float*)(ws + 33722048);
    float*    ln2wf = (float*)(ws + 33723072);
    float*    ln2bf = (float*)(ws + 33724096);
    float*    ln3wf = (float*)(ws + 33725120);
    float*    ln3bf = (float*)(ws + 33726144);
    const size_t NEED_SMALL = 33727184;

    if (ws_size < NEED_SMALL) {
        int nwords = out_size / 2;
        ksentinel<<<(nwords + 255) / 256, 256, 0, stream>>>((uint_t*)d_out, nwords);
        return;
    }

    kpf<<<4256, 256, 0, stream>>>(x, w1, w2, b1, b2, ln1w, ln1b,
                                  ln2w, ln2b, map_b, ln3w, ln3b,
                                  conv_w, map_w, xT,
                                  w1b, w2b, b1f, b2f, ln1wf, ln1bf,
                                  ln2wf, ln2bf, mbf, ln3wf, ln3bf, wfrag);
    k1f<<<1024, 512, 0, stream>>>(xT, w1b, b1f, w2b, b2f, ln1wf, ln1bf, y1);
    k23<<<NPIX / 64, 512, 0, stream>>>(x, y1, xT, wfrag, mbf,
                                       ln2wf, ln2bf, ln3wf, ln3bf, d_out);
}